// Round 4
// baseline (2548.193 us; speedup 1.0000x reference)
//
#include <hip/hip_runtime.h>
#include <hip/hip_bf16.h>
#include <math.h>

#define NN   6000
#define DD   128
#define RR   1000
#define CAP  96      // max nnz/row for adj (mean ~33, std ~5.7 -> 11 sigma)
#define CAPR 48      // max nnz/row for rel_adj (mean ~6)
#define MAXN_F 0.996f

// ---------------- module-global scratch (no d_ws dependence) ----------------
__device__ int      g_dt[19];               // per-input dtype: 1 = bf16, 0 = f32
__device__ unsigned g_csri[2][NN * CAP];    // neighbor col index
__device__ float    g_csrv[2][NN * CAP];    // neighbor adj value (f32 exact)
__device__ int      g_cnt[2][NN];
__device__ float    g_hh[2][NN * DD];
__device__ float    g_seq[NN * 3 * DD];
__device__ float    g_es[2][NN];
__device__ float    g_ed[2][NN];
__device__ float    g_hb[2][DD];
__device__ float    g_h[NN * DD];
__device__ float    g_t[NN * DD];

// dtype-generic input load (element index), flag passed explicitly
__device__ __forceinline__ float ldin(const void* p, size_t i, int bf) {
    if (bf)
        return __uint_as_float(((unsigned)((const unsigned short*)p)[i]) << 16);
    return ((const float*)p)[i];
}

// Per-array dtype vote: low 16 bits of each word are mantissa noise for f32
// (exp-field uniform -> ~16% in [100,140]) but a real bf16 value for bf16 data
// (~100% in range for |x| in [2^-27, 2^13]). Zero low-halves abstain; tie -> f32.
__global__ void detect_dt(const unsigned* __restrict__ p, int nelem, int slot) {
    __shared__ int votes[2];
    if (threadIdx.x == 0) { votes[0] = 0; votes[1] = 0; }
    __syncthreads();
    int nwords = nelem / 2;               // safe to read under both dtypes
    if (nwords > 0) {
        int nsamp = nwords < 4096 ? nwords : 4096;
        int stride = nwords / nsamp; if (stride < 1) stride = 1;
        for (int s = threadIdx.x; s < nsamp; s += blockDim.x) {
            unsigned w = p[(size_t)s * stride];
            unsigned lo = w & 0xFFFFu;
            if (lo) {
                unsigned e = (lo >> 7) & 0xFFu;
                if (e >= 100u && e <= 140u) atomicAdd(&votes[1], 1);
                else                        atomicAdd(&votes[0], 1);
            }
        }
    }
    __syncthreads();
    if (threadIdx.x == 0) g_dt[slot] = (votes[1] > votes[0]) ? 1 : 0;
}

// All-thread block reduce over 128 threads; every thread gets the sum.
__device__ __forceinline__ float block_reduce_sum128(float v, float* red) {
    int d = threadIdx.x;
    red[d] = v; __syncthreads();
    for (int s = 64; s > 0; s >>= 1) {
        if (d < s) red[d] += red[d + s];
        __syncthreads();
    }
    float r = red[0]; __syncthreads();
    return r;
}

// ---------------- CSR build from dense adj (NN x NN) ----------------
__global__ void build_csr(const void* __restrict__ A, int which, int slot) {
    int n = blockIdx.x;
    const int bf = g_dt[slot];
    __shared__ int c;
    if (threadIdx.x == 0) c = 0;
    __syncthreads();
    for (int m = threadIdx.x; m < NN; m += blockDim.x) {
        float a = ldin(A, (size_t)n * NN + m, bf);
        if (a > 0.f) {
            int p = atomicAdd(&c, 1);
            if (p < CAP) {
                g_csri[which][(size_t)n * CAP + p] = (unsigned)m;
                g_csrv[which][(size_t)n * CAP + p] = a;
            }
        }
    }
    __syncthreads();
    if (threadIdx.x == 0) g_cnt[which][n] = min(c, CAP);
}

// ---------------- Relation aggregator: (radj @ rel) / rowsum; radj in {0,1} ----------------
__global__ void rel_agg_kernel(const void* __restrict__ radj, const void* __restrict__ rel,
                               int slot_radj, int slot_rel,
                               float* __restrict__ outA, float* __restrict__ outB) {
    int n = blockIdx.x, d = threadIdx.x;  // 128 threads
    const int bfa = g_dt[slot_radj], bfr = g_dt[slot_rel];
    __shared__ int list[CAPR];
    __shared__ int cs;
    if (d == 0) cs = 0;
    __syncthreads();
    for (int m = d; m < RR; m += 128) {
        float a = ldin(radj, (size_t)n * RR + m, bfa);
        if (a > 0.f) { int p = atomicAdd(&cs, 1); if (p < CAPR) list[p] = m; }
    }
    __syncthreads();
    int c = min(cs, CAPR);
    float acc = 0.f;
    for (int j = 0; j < c; j++) acc += ldin(rel, (size_t)list[j] * DD + d, bfr);
    float r = c ? acc / (float)c : 0.f;  // rowsum == count (values are exactly 1.0)
    outA[(size_t)n * 256 + 128 + d] = r;
    outB[(size_t)n * 256 + 128 + d] = r;
}

// ---------------- GAT ----------------
__global__ void copy_ent_seq(const void* __restrict__ ent, int slot) {
    int n = blockIdx.x, d = threadIdx.x;  // 128
    g_seq[(size_t)n * 384 + d] = ldin(ent, (size_t)n * DD + d, g_dt[slot]);
}

// h[h][n][e] = sum_d x[n][d] * W[h][d][e]; es/ed per-head dot with a_src/a_dst
__global__ __launch_bounds__(256) void gat_proj(
        int layer, const void* __restrict__ W,
        const void* __restrict__ a_src, const void* __restrict__ a_dst) {
    int n = blockIdx.x, tid = threadIdx.x;  // 256 threads: (head, e)
    int h = tid >> 7, e = tid & 127;
    const int bfw = g_dt[8], bfs = g_dt[9], bfd = g_dt[10];
    __shared__ float xs[128];
    __shared__ float red[256];
    if (tid < 128) xs[tid] = g_seq[(size_t)n * 384 + layer * 128 + tid];
    __syncthreads();
    size_t wbase = ((size_t)layer * 2 + h) * DD * DD;
    float acc = 0.f;
    for (int d = 0; d < DD; d++) acc += xs[d] * ldin(W, wbase + (size_t)d * DD + e, bfw);
    g_hh[h][(size_t)n * DD + e] = acc;

    size_t abase = ((size_t)layer * 2 + h) * DD;
    red[tid] = acc * ldin(a_src, abase + e, bfs); __syncthreads();
    for (int s = 64; s > 0; s >>= 1) { if ((tid & 127) < s) red[tid] += red[tid + s]; __syncthreads(); }
    if ((tid & 127) == 0) g_es[h][n] = red[tid];
    __syncthreads();
    red[tid] = acc * ldin(a_dst, abase + e, bfd); __syncthreads();
    for (int s = 64; s > 0; s >>= 1) { if ((tid & 127) < s) red[tid] += red[tid + s]; __syncthreads(); }
    if ((tid & 127) == 0) g_ed[h][n] = red[tid];
}

// masked softmax over CSR neighbors + weighted sum (2 heads) + mean + elu + row-normalize
__global__ void gat_attn(int which, int layer) {
    int n = blockIdx.x, d = threadIdx.x;  // 128
    int c = g_cnt[which][n];
    float es0 = g_es[0][n], es1 = g_es[1][n];
    float m0 = -1e30f, m1 = -1e30f;
    for (int j = 0; j < c; j++) {
        int mI = (int)g_csri[which][(size_t)n * CAP + j];
        float e0 = es0 + g_ed[0][mI]; e0 = e0 > 0.f ? e0 : 0.2f * e0;
        float e1 = es1 + g_ed[1][mI]; e1 = e1 > 0.f ? e1 : 0.2f * e1;
        m0 = fmaxf(m0, e0); m1 = fmaxf(m1, e1);
    }
    float s0 = 0.f, s1 = 0.f, a0 = 0.f, a1 = 0.f;
    for (int j = 0; j < c; j++) {
        int mI = (int)g_csri[which][(size_t)n * CAP + j];
        float e0 = es0 + g_ed[0][mI]; e0 = e0 > 0.f ? e0 : 0.2f * e0;
        float e1 = es1 + g_ed[1][mI]; e1 = e1 > 0.f ? e1 : 0.2f * e1;
        float w0 = expf(e0 - m0), w1 = expf(e1 - m1);
        s0 += w0; s1 += w1;
        a0 += w0 * g_hh[0][(size_t)mI * DD + d];
        a1 += w1 * g_hh[1][(size_t)mI * DD + d];
    }
    float o = (c > 0) ? 0.5f * (a0 / fmaxf(s0, 1e-30f) + a1 / fmaxf(s1, 1e-30f)) : 0.f;
    o = o > 0.f ? o : expm1f(o);  // elu
    __shared__ float red[128];
    float ss = block_reduce_sum128(o * o, red);
    float nrm = sqrtf(ss);
    float r = o / fmaxf(nrm, 1e-12f);
    g_seq[(size_t)n * 384 + (layer + 1) * 128 + d] = r;
}

// ---------------- per-node MHA over Lr=3 + residual + LN + mean ----------------
__global__ __launch_bounds__(256) void mha_kernel(
        const void* __restrict__ Wq, const void* __restrict__ Wk,
        const void* __restrict__ Wv, const void* __restrict__ Wfc,
        const void* __restrict__ g, const void* __restrict__ b,
        float* __restrict__ out) {
    int n = blockIdx.x, tid = threadIdx.x;
    const int bq = g_dt[11], bk = g_dt[12], bv = g_dt[13], bfc = g_dt[14];
    const int bg = g_dt[15], bb = g_dt[16];
    __shared__ float S[3][128], q[3][256], k[3][256], v[3][256], o[3][256], oo[3][128];
    __shared__ float att[2][3][3];
    __shared__ float mu[3], rstd[3];
    for (int t = tid; t < 384; t += 256) S[t >> 7][t & 127] = g_seq[(size_t)n * 384 + t];
    __syncthreads();
    for (int t = tid; t < 768; t += 256) {
        int l = t >> 8, e = t & 255;
        float aq = 0.f, ak = 0.f, av = 0.f;
        for (int d = 0; d < 128; d++) {
            float s = S[l][d];
            aq += s * ldin(Wq, (size_t)d * 256 + e, bq);
            ak += s * ldin(Wk, (size_t)d * 256 + e, bk);
            av += s * ldin(Wv, (size_t)d * 256 + e, bv);
        }
        q[l][e] = aq; k[l][e] = ak; v[l][e] = av;
    }
    __syncthreads();
    if (tid < 18) {
        int h = tid / 9, lm = tid % 9, l = lm / 3, m = lm % 3;
        float acc = 0.f;
        for (int d = 0; d < 128; d++) acc += q[l][h * 128 + d] * k[m][h * 128 + d];
        att[h][l][m] = acc * 0.08838834764831845f;  // 1/sqrt(128)
    }
    __syncthreads();
    if (tid < 6) {
        int h = tid / 3, l = tid % 3;
        float mx = fmaxf(att[h][l][0], fmaxf(att[h][l][1], att[h][l][2]));
        float e0 = expf(att[h][l][0] - mx), e1 = expf(att[h][l][1] - mx), e2 = expf(att[h][l][2] - mx);
        float s = fmaxf(e0 + e1 + e2, 1e-30f);
        att[h][l][0] = e0 / s; att[h][l][1] = e1 / s; att[h][l][2] = e2 / s;
    }
    __syncthreads();
    for (int t = tid; t < 768; t += 256) {
        int l = t >> 8, e = t & 255, h = e >> 7;
        o[l][e] = att[h][l][0] * v[0][e] + att[h][l][1] * v[1][e] + att[h][l][2] * v[2][e];
    }
    __syncthreads();
    for (int t = tid; t < 384; t += 256) {
        int l = t >> 7, dd = t & 127;
        float acc = S[l][dd];  // residual
        for (int e = 0; e < 256; e++) acc += o[l][e] * ldin(Wfc, (size_t)e * 128 + dd, bfc);
        oo[l][dd] = acc;
    }
    __syncthreads();
    if (tid < 3) {
        float s = 0.f, ss = 0.f;
        for (int d = 0; d < 128; d++) { float x = oo[tid][d]; s += x; ss += x * x; }
        float m = s / 128.f; mu[tid] = m;
        rstd[tid] = rsqrtf(ss / 128.f - m * m + 1e-6f);
    }
    __syncthreads();
    if (tid < 128) {
        float acc = 0.f;
        for (int l = 0; l < 3; l++) acc += (oo[l][tid] - mu[l]) * rstd[l];
        out[(size_t)n * 256 + tid] = ldin(g, tid, bg) * (acc / 3.f) + ldin(b, tid, bb);
    }
}

// ---------------- Hyperbolic GCN ----------------
__global__ void hgc_bias(const void* __restrict__ hgc_b) {
    int i = blockIdx.x, d = threadIdx.x;  // 2 blocks x 128
    __shared__ float red[128];
    float bv = ldin(hgc_b, (size_t)i * DD + d, g_dt[18]);
    float ss = block_reduce_sum128(bv * bv, red);
    float nrm = fmaxf(sqrtf(ss), 1e-15f);
    float v = tanhf(nrm) / nrm * bv;
    float vn = tanhf(nrm);
    if (vn > MAXN_F) v *= MAXN_F / vn;
    g_hb[i][d] = v;
}

__global__ void hgc_init(const void* __restrict__ ent, int slot) {
    int n = blockIdx.x, d = threadIdx.x;
    __shared__ float red[128];
    float x = ldin(ent, (size_t)n * DD + d, g_dt[slot]);
    float ss = block_reduce_sum128(x * x, red);
    float nrm = fmaxf(sqrtf(ss), 1e-15f);
    float v = tanhf(nrm) / nrm * x;
    float vn = tanhf(nrm);
    if (vn > MAXN_F) v *= MAXN_F / vn;
    g_h[(size_t)n * DD + d] = v;
}

// u=logmap0(h); mv=u@W.T; v=proj(expmap0(mv)); h2=proj(mobius_add(v,hb)); t=logmap0(h2)
__global__ void hgc_linear(const void* __restrict__ W, int layer) {
    int n = blockIdx.x, d = threadIdx.x;  // 128
    const int bfw = g_dt[17];
    __shared__ float red[128];
    __shared__ float u[128];
    float hv = g_h[(size_t)n * DD + d];
    float ss = block_reduce_sum128(hv * hv, red);
    float nrm = fmaxf(sqrtf(ss), 1e-15f);
    u[d] = atanhf(fminf(nrm, 1.f - 1e-7f)) / nrm * hv;
    __syncthreads();
    size_t wbase = (size_t)layer * DD * DD;
    float mv = 0.f;
    for (int j = 0; j < DD; j++) mv += u[j] * ldin(W, wbase + (size_t)d * DD + j, bfw);
    float ss2 = block_reduce_sum128(mv * mv, red);
    float nm = fmaxf(sqrtf(ss2), 1e-15f);
    float x = tanhf(nm) / nm * mv;
    float xn = tanhf(nm);
    if (xn > MAXN_F) { x *= MAXN_F / xn; xn = MAXN_F; }
    // mobius_add(x, hb)
    float y = g_hb[layer][d];
    float x2 = xn * xn;
    float y2 = block_reduce_sum128(y * y, red);
    float xy = block_reduce_sum128(x * y, red);
    float num = (1.f + 2.f * xy + y2) * x + (1.f - x2) * y;
    float den = 1.f + 2.f * xy + x2 * y2;
    den = (fabsf(den) < 1e-15f) ? 1e-15f : den;
    float hv2 = num / den;
    float s3 = block_reduce_sum128(hv2 * hv2, red);
    float nn = fmaxf(sqrtf(s3), 1e-15f);
    if (nn > MAXN_F) { hv2 *= MAXN_F / nn; nn = MAXN_F; }
    float sc3 = atanhf(fminf(nn, 1.f - 1e-7f)) / nn;
    g_t[(size_t)n * DD + d] = sc3 * hv2;
}

// s = adj@t (CSR); h = proj(expmap0(s)); relu in tangent; expmap0 + proj
__global__ void hgc_agg(int which) {
    int n = blockIdx.x, d = threadIdx.x;
    __shared__ float red[128];
    int c = g_cnt[which][n];
    float acc = 0.f;
    for (int j = 0; j < c; j++) {
        acc += g_csrv[which][(size_t)n * CAP + j]
             * g_t[(size_t)g_csri[which][(size_t)n * CAP + j] * DD + d];
    }
    float ss = block_reduce_sum128(acc * acc, red);
    float nm = fmaxf(sqrtf(ss), 1e-15f);
    float x = tanhf(nm) / nm * acc;
    float xn = tanhf(nm);
    if (xn > MAXN_F) { x *= MAXN_F / xn; xn = MAXN_F; }
    float nrm = fmaxf(xn, 1e-15f);
    float u = atanhf(fminf(nrm, 1.f - 1e-7f)) / nrm * x;
    u = fmaxf(u, 0.f);
    float ss2 = block_reduce_sum128(u * u, red);
    float nm2 = fmaxf(sqrtf(ss2), 1e-15f);
    float x2 = tanhf(nm2) / nm2 * u;
    float xn2 = tanhf(nm2);
    if (xn2 > MAXN_F) x2 *= MAXN_F / xn2;
    g_h[(size_t)n * DD + d] = x2;
}

__global__ void hgc_out(const void* __restrict__ ent, int slot, float* __restrict__ out) {
    int n = blockIdx.x, d = threadIdx.x;
    __shared__ float red[128];
    float hv = g_h[(size_t)n * DD + d];
    float ss = block_reduce_sum128(hv * hv, red);
    float nrm = fmaxf(sqrtf(ss), 1e-15f);
    float u = atanhf(fminf(nrm, 1.f - 1e-7f)) / nrm * hv;
    out[(size_t)n * 256 + d] = ldin(ent, (size_t)n * DD + d, g_dt[slot]) + u;
}

extern "C" void kernel_launch(void* const* d_in, const int* in_sizes, int n_in,
                              void* d_out, int out_size, void* d_ws, size_t ws_size,
                              hipStream_t stream) {
    const void* ent_sr = d_in[0];
    const void* ent_tg = d_in[1];
    const void* rel_sr = d_in[2];
    const void* rel_tg = d_in[3];
    const void* adj_sr = d_in[4];
    const void* adj_tg = d_in[5];
    const void* rel_adj_sr = d_in[6];
    const void* rel_adj_tg = d_in[7];
    const void* gat_W     = d_in[8];
    const void* gat_a_src = d_in[9];
    const void* gat_a_dst = d_in[10];
    const void* Wq  = d_in[11];
    const void* Wk  = d_in[12];
    const void* Wv  = d_in[13];
    const void* Wfc = d_in[14];
    const void* ln_g = d_in[15];
    const void* ln_b = d_in[16];
    const void* hgc_W = d_in[17];
    const void* hgc_b = d_in[18];

    float* out  = (float*)d_out;
    float* out0 = out;
    float* out1 = out + (size_t)NN * 256;
    float* out2 = out + (size_t)2 * NN * 256;
    float* out3 = out + (size_t)3 * NN * 256;

    for (int i = 0; i < 19 && i < n_in; i++)
        detect_dt<<<1, 256, 0, stream>>>((const unsigned*)d_in[i], in_sizes[i], i);

    build_csr<<<NN, 256, 0, stream>>>(adj_sr, 0, 4);
    build_csr<<<NN, 256, 0, stream>>>(adj_tg, 1, 5);

    rel_agg_kernel<<<NN, 128, 0, stream>>>(rel_adj_sr, rel_sr, 6, 2, out0, out2);
    rel_agg_kernel<<<NN, 128, 0, stream>>>(rel_adj_tg, rel_tg, 7, 3, out1, out3);

    for (int br = 0; br < 2; br++) {
        const void* ent = br ? ent_tg : ent_sr;
        float* outc = br ? out1 : out0;
        copy_ent_seq<<<NN, 128, 0, stream>>>(ent, br);
        for (int layer = 0; layer < 2; layer++) {
            gat_proj<<<NN, 256, 0, stream>>>(layer, gat_W, gat_a_src, gat_a_dst);
            gat_attn<<<NN, 128, 0, stream>>>(br, layer);
        }
        mha_kernel<<<NN, 256, 0, stream>>>(Wq, Wk, Wv, Wfc, ln_g, ln_b, outc);
    }

    hgc_bias<<<2, 128, 0, stream>>>(hgc_b);
    for (int br = 0; br < 2; br++) {
        const void* ent = br ? ent_tg : ent_sr;
        float* outc = br ? out3 : out2;
        hgc_init<<<NN, 128, 0, stream>>>(ent, br);
        for (int layer = 0; layer < 2; layer++) {
            hgc_linear<<<NN, 128, 0, stream>>>(hgc_W, layer);
            hgc_agg<<<NN, 128, 0, stream>>>(br);
        }
        hgc_out<<<NN, 128, 0, stream>>>(ent, br, outc);
    }
}

// Round 5
// 1164.488 us; speedup vs baseline: 2.1883x; 2.1883x over previous
//
#include <hip/hip_runtime.h>
#include <hip/hip_bf16.h>
#include <math.h>

#define NN   6000
#define DD   128
#define RR   1000
#define CAP  96
#define CAPR 48
#define MAXN_F 0.996f

// ---------------- module-global scratch ----------------
__device__ int      g_dt[19];               // per-input dtype: 1 = bf16, 0 = f32
__device__ unsigned g_csri[2][NN * CAP];
__device__ float    g_csrv[2][NN * CAP];
__device__ int      g_cnt[2][NN];
__device__ float    g_seq[NN * 3 * DD];     // [n][l][d] == [(n*3+l)][d]
__device__ float    g_hh[NN * 256];         // [n][h*128+e]
__device__ float    g_es[2][NN];
__device__ float    g_ed[2][NN];
__device__ float    g_qkv[NN * 3 * 768];    // [(n*3+l)][q|k|v]
__device__ float    g_o[NN * 3 * 256];
__device__ float    g_fc[NN * 3 * DD];
__device__ float    g_u[NN * DD];
__device__ float    g_mv[NN * DD];
__device__ float    g_h[NN * DD];
__device__ float    g_t[NN * DD];
__device__ float    g_hb[2][DD];
// packed f32 weights
__device__ float    g_Wgat[2][DD * 256];    // [l][d][h*128+e]
__device__ float    g_Wqkv[DD * 768];       // [d][Wq|Wk|Wv]
__device__ float    g_Wfc[256 * DD];
__device__ float    g_WhgcT[2][DD * DD];    // [l][j][d] = hgc_W[l][d][j]

__device__ __forceinline__ float ldin(const void* p, size_t i, int bf) {
    if (bf) return __uint_as_float(((unsigned)((const unsigned short*)p)[i]) << 16);
    return ((const float*)p)[i];
}

struct P19 { const void* p[19]; };

__global__ void detect_all(P19 ptrs) {
    const int sizes[19] = {768000,768000,128000,128000,36000000,36000000,6000000,6000000,
                           65536,512,512,32768,32768,32768,32768,128,128,32768,256};
    int slot = blockIdx.x;
    const unsigned* p = (const unsigned*)ptrs.p[slot];
    __shared__ int votes[2];
    if (threadIdx.x == 0) { votes[0] = 0; votes[1] = 0; }
    __syncthreads();
    int nwords = sizes[slot] / 2;
    if (nwords > 0) {
        int nsamp = nwords < 4096 ? nwords : 4096;
        int stride = nwords / nsamp; if (stride < 1) stride = 1;
        for (int s = threadIdx.x; s < nsamp; s += blockDim.x) {
            unsigned lo = p[(size_t)s * stride] & 0xFFFFu;
            if (lo) {
                unsigned e = (lo >> 7) & 0xFFu;
                if (e >= 100u && e <= 140u) atomicAdd(&votes[1], 1);
                else                        atomicAdd(&votes[0], 1);
            }
        }
    }
    __syncthreads();
    if (threadIdx.x == 0) g_dt[slot] = (votes[1] > votes[0]) ? 1 : 0;
}

__global__ void prep_weights(const void* gatW, const void* Wq, const void* Wk, const void* Wv,
                             const void* Wfc, const void* hgcW) {
    int stride = gridDim.x * blockDim.x;
    int base = blockIdx.x * blockDim.x + threadIdx.x;
    const int b8 = g_dt[8], b11 = g_dt[11], b12 = g_dt[12], b13 = g_dt[13],
              b14 = g_dt[14], b17 = g_dt[17];
    for (int i = base; i < 65536; i += stride) {        // gat_W [l][h][d][e]
        int e = i & 127, d = (i >> 7) & 127, h = (i >> 14) & 1, l = (i >> 15) & 1;
        g_Wgat[l][(d << 8) + (h << 7) + e] = ldin(gatW, i, b8);
    }
    for (int i = base; i < 32768; i += stride) {        // Wq/Wk/Wv [d][e]
        int d = i >> 8, e = i & 255;
        g_Wqkv[d * 768 + e]       = ldin(Wq, i, b11);
        g_Wqkv[d * 768 + 256 + e] = ldin(Wk, i, b12);
        g_Wqkv[d * 768 + 512 + e] = ldin(Wv, i, b13);
    }
    for (int i = base; i < 32768; i += stride) g_Wfc[i] = ldin(Wfc, i, b14);
    for (int i = base; i < 32768; i += stride) {        // hgc_W [l][d][j] -> T
        int j = i & 127, d = (i >> 7) & 127, l = i >> 14;
        g_WhgcT[l][j * 128 + d] = ldin(hgcW, i, b17);
    }
}

__device__ __forceinline__ float block_reduce_sum128(float v, float* red) {
    int d = threadIdx.x;
    red[d] = v; __syncthreads();
    for (int s = 64; s > 0; s >>= 1) {
        if (d < s) red[d] += red[d + s];
        __syncthreads();
    }
    float r = red[0]; __syncthreads();
    return r;
}

// ---------------- tiled f32 GEMM: C[M x N] = A[M x K] @ B[K x N] ----------------
// N multiple of 64, K multiple of 32. grid = (N/64, ceil(M/64)), 256 threads.
__global__ __launch_bounds__(256) void gemm64(const float* __restrict__ A, int lda,
                                              const float* __restrict__ B, int ldb,
                                              float* __restrict__ C, int ldc,
                                              int M, int K) {
    __shared__ float As[32][72];   // [k][m], row stride 72 floats (288 B, 16B-aligned)
    __shared__ float Bs[32][64];   // [k][n]
    int bm = blockIdx.y * 64, bn = blockIdx.x * 64;
    int tid = threadIdx.x;
    int tm4 = tid >> 4, tn4 = tid & 15;
    float acc[4][4] = {};
    for (int k0 = 0; k0 < K; k0 += 32) {
        #pragma unroll
        for (int i = 0; i < 2; i++) {
            int idx = tid * 2 + i;
            int m = idx >> 3, kk = idx & 7;
            float4 a = {0.f, 0.f, 0.f, 0.f};
            if (bm + m < M) a = *(const float4*)(A + (size_t)(bm + m) * lda + k0 + kk * 4);
            As[kk * 4 + 0][m] = a.x; As[kk * 4 + 1][m] = a.y;
            As[kk * 4 + 2][m] = a.z; As[kk * 4 + 3][m] = a.w;
        }
        #pragma unroll
        for (int i = 0; i < 2; i++) {
            int idx = tid * 2 + i;
            int r = idx >> 4, c4 = idx & 15;
            *(float4*)&Bs[r][c4 * 4] = *(const float4*)(B + (size_t)(k0 + r) * ldb + bn + c4 * 4);
        }
        __syncthreads();
        #pragma unroll
        for (int k = 0; k < 32; k++) {
            float4 a4 = *(float4*)&As[k][tm4 * 4];
            float4 b4 = *(float4*)&Bs[k][tn4 * 4];
            float av[4] = {a4.x, a4.y, a4.z, a4.w};
            float bv[4] = {b4.x, b4.y, b4.z, b4.w};
            #pragma unroll
            for (int i = 0; i < 4; i++)
                #pragma unroll
                for (int j = 0; j < 4; j++)
                    acc[i][j] = fmaf(av[i], bv[j], acc[i][j]);
        }
        __syncthreads();
    }
    #pragma unroll
    for (int i = 0; i < 4; i++) {
        int m = bm + tm4 * 4 + i;
        if (m < M) {
            #pragma unroll
            for (int j = 0; j < 4; j++)
                C[(size_t)m * ldc + bn + tn4 * 4 + j] = acc[i][j];
        }
    }
}

// ---------------- CSR build ----------------
__global__ void build_csr(const void* __restrict__ A, int which, int slot) {
    int n = blockIdx.x;
    const int bf = g_dt[slot];
    __shared__ int c;
    if (threadIdx.x == 0) c = 0;
    __syncthreads();
    for (int m = threadIdx.x; m < NN; m += blockDim.x) {
        float a = ldin(A, (size_t)n * NN + m, bf);
        if (a > 0.f) {
            int p = atomicAdd(&c, 1);
            if (p < CAP) {
                g_csri[which][(size_t)n * CAP + p] = (unsigned)m;
                g_csrv[which][(size_t)n * CAP + p] = a;
            }
        }
    }
    __syncthreads();
    if (threadIdx.x == 0) g_cnt[which][n] = min(c, CAP);
}

// ---------------- Relation aggregator ----------------
__global__ void rel_agg_kernel(const void* __restrict__ radj, const void* __restrict__ rel,
                               int slot_radj, int slot_rel,
                               float* __restrict__ outA, float* __restrict__ outB) {
    int n = blockIdx.x, d = threadIdx.x;
    const int bfa = g_dt[slot_radj], bfr = g_dt[slot_rel];
    __shared__ int list[CAPR];
    __shared__ int cs;
    if (d == 0) cs = 0;
    __syncthreads();
    for (int m = d; m < RR; m += 128) {
        float a = ldin(radj, (size_t)n * RR + m, bfa);
        if (a > 0.f) { int p = atomicAdd(&cs, 1); if (p < CAPR) list[p] = m; }
    }
    __syncthreads();
    int c = min(cs, CAPR);
    float acc = 0.f;
    for (int j = 0; j < c; j++) acc += ldin(rel, (size_t)list[j] * DD + d, bfr);
    float r = c ? acc / (float)c : 0.f;
    outA[(size_t)n * 256 + 128 + d] = r;
    outB[(size_t)n * 256 + 128 + d] = r;
}

// ---------------- GAT ----------------
__global__ void copy_ent_seq(const void* __restrict__ ent, int slot) {
    int n = blockIdx.x, d = threadIdx.x;
    g_seq[(size_t)n * 384 + d] = ldin(ent, (size_t)n * DD + d, g_dt[slot]);
}

// es/ed from projected g_hh
__global__ __launch_bounds__(256) void gat_scores(int layer, const void* __restrict__ a_src,
                                                  const void* __restrict__ a_dst) {
    int n = blockIdx.x, tid = threadIdx.x;
    int h = tid >> 7, e = tid & 127;
    const int bfs = g_dt[9], bfd = g_dt[10];
    __shared__ float red[256];
    float hv = g_hh[(size_t)n * 256 + tid];
    size_t abase = ((size_t)layer * 2 + h) * DD;
    red[tid] = hv * ldin(a_src, abase + e, bfs); __syncthreads();
    for (int s = 64; s > 0; s >>= 1) { if ((tid & 127) < s) red[tid] += red[tid + s]; __syncthreads(); }
    if ((tid & 127) == 0) g_es[h][n] = red[tid];
    __syncthreads();
    red[tid] = hv * ldin(a_dst, abase + e, bfd); __syncthreads();
    for (int s = 64; s > 0; s >>= 1) { if ((tid & 127) < s) red[tid] += red[tid + s]; __syncthreads(); }
    if ((tid & 127) == 0) g_ed[h][n] = red[tid];
}

__global__ void gat_attn(int which, int layer) {
    int n = blockIdx.x, d = threadIdx.x;  // 128
    int c = g_cnt[which][n];
    float es0 = g_es[0][n], es1 = g_es[1][n];
    float m0 = -1e30f, m1 = -1e30f;
    for (int j = 0; j < c; j++) {
        int mI = (int)g_csri[which][(size_t)n * CAP + j];
        float e0 = es0 + g_ed[0][mI]; e0 = e0 > 0.f ? e0 : 0.2f * e0;
        float e1 = es1 + g_ed[1][mI]; e1 = e1 > 0.f ? e1 : 0.2f * e1;
        m0 = fmaxf(m0, e0); m1 = fmaxf(m1, e1);
    }
    float s0 = 0.f, s1 = 0.f, a0 = 0.f, a1 = 0.f;
    for (int j = 0; j < c; j++) {
        int mI = (int)g_csri[which][(size_t)n * CAP + j];
        float e0 = es0 + g_ed[0][mI]; e0 = e0 > 0.f ? e0 : 0.2f * e0;
        float e1 = es1 + g_ed[1][mI]; e1 = e1 > 0.f ? e1 : 0.2f * e1;
        float w0 = expf(e0 - m0), w1 = expf(e1 - m1);
        s0 += w0; s1 += w1;
        a0 += w0 * g_hh[(size_t)mI * 256 + d];
        a1 += w1 * g_hh[(size_t)mI * 256 + 128 + d];
    }
    float o = (c > 0) ? 0.5f * (a0 / fmaxf(s0, 1e-30f) + a1 / fmaxf(s1, 1e-30f)) : 0.f;
    o = o > 0.f ? o : expm1f(o);  // elu
    __shared__ float red[128];
    float ss = block_reduce_sum128(o * o, red);
    float r = o / fmaxf(sqrtf(ss), 1e-12f);
    g_seq[(size_t)n * 384 + (layer + 1) * 128 + d] = r;
}

// ---------------- MHA: per-node attention on precomputed q,k,v ----------------
__global__ __launch_bounds__(256) void mha_attn() {
    int n = blockIdx.x, tid = threadIdx.x;
    __shared__ float qs[3][256], ks[3][256], vs[3][256];
    __shared__ float att[2][3][3];
    for (int t = tid; t < 768; t += 256) {
        int l = t >> 8, e = t & 255;
        size_t base = (size_t)(n * 3 + l) * 768;
        qs[l][e] = g_qkv[base + e];
        ks[l][e] = g_qkv[base + 256 + e];
        vs[l][e] = g_qkv[base + 512 + e];
    }
    __syncthreads();
    if (tid < 18) {
        int h = tid / 9, lm = tid % 9, l = lm / 3, m = lm % 3;
        float acc = 0.f;
        for (int d = 0; d < 128; d++) acc += qs[l][h * 128 + d] * ks[m][h * 128 + d];
        att[h][l][m] = acc * 0.08838834764831845f;
    }
    __syncthreads();
    if (tid < 6) {
        int h = tid / 3, l = tid % 3;
        float mx = fmaxf(att[h][l][0], fmaxf(att[h][l][1], att[h][l][2]));
        float e0 = expf(att[h][l][0] - mx), e1 = expf(att[h][l][1] - mx), e2 = expf(att[h][l][2] - mx);
        float s = fmaxf(e0 + e1 + e2, 1e-30f);
        att[h][l][0] = e0 / s; att[h][l][1] = e1 / s; att[h][l][2] = e2 / s;
    }
    __syncthreads();
    for (int t = tid; t < 768; t += 256) {
        int l = t >> 8, e = t & 255, h = e >> 7;
        g_o[(size_t)(n * 3 + l) * 256 + e] =
            att[h][l][0] * vs[0][e] + att[h][l][1] * vs[1][e] + att[h][l][2] * vs[2][e];
    }
}

// residual + LN + mean over l
__global__ void mha_out(const void* __restrict__ g, const void* __restrict__ b,
                        float* __restrict__ out) {
    int n = blockIdx.x, d = threadIdx.x;  // 128
    const int bg = g_dt[15], bb = g_dt[16];
    __shared__ float red[128];
    float ool[3], mu[3], rstd[3];
    #pragma unroll
    for (int l = 0; l < 3; l++)
        ool[l] = g_fc[(size_t)(n * 3 + l) * 128 + d] + g_seq[(size_t)(n * 3 + l) * 128 + d];
    #pragma unroll
    for (int l = 0; l < 3; l++) {
        float s  = block_reduce_sum128(ool[l], red);
        float ss = block_reduce_sum128(ool[l] * ool[l], red);
        mu[l] = s / 128.f;
        rstd[l] = rsqrtf(ss / 128.f - mu[l] * mu[l] + 1e-6f);
    }
    float acc = 0.f;
    #pragma unroll
    for (int l = 0; l < 3; l++) acc += (ool[l] - mu[l]) * rstd[l];
    out[(size_t)n * 256 + d] = ldin(g, d, bg) * (acc / 3.f) + ldin(b, d, bb);
}

// ---------------- Hyperbolic GCN ----------------
__global__ void hgc_bias(const void* __restrict__ hgc_b) {
    int i = blockIdx.x, d = threadIdx.x;
    __shared__ float red[128];
    float bv = ldin(hgc_b, (size_t)i * DD + d, g_dt[18]);
    float ss = block_reduce_sum128(bv * bv, red);
    float nrm = fmaxf(sqrtf(ss), 1e-15f);
    float v = tanhf(nrm) / nrm * bv;
    float vn = tanhf(nrm);
    if (vn > MAXN_F) v *= MAXN_F / vn;
    g_hb[i][d] = v;
}

__global__ void hgc_init(const void* __restrict__ ent, int slot) {
    int n = blockIdx.x, d = threadIdx.x;
    __shared__ float red[128];
    float x = ldin(ent, (size_t)n * DD + d, g_dt[slot]);
    float ss = block_reduce_sum128(x * x, red);
    float nrm = fmaxf(sqrtf(ss), 1e-15f);
    float v = tanhf(nrm) / nrm * x;
    float vn = tanhf(nrm);
    if (vn > MAXN_F) v *= MAXN_F / vn;
    g_h[(size_t)n * DD + d] = v;
}

__global__ void hgc_log() {
    int n = blockIdx.x, d = threadIdx.x;
    __shared__ float red[128];
    float hv = g_h[(size_t)n * DD + d];
    float ss = block_reduce_sum128(hv * hv, red);
    float nrm = fmaxf(sqrtf(ss), 1e-15f);
    g_u[(size_t)n * DD + d] = atanhf(fminf(nrm, 1.f - 1e-7f)) / nrm * hv;
}

// after mv GEMM: proj(expmap0(mv)); mobius_add(.,hb); proj; logmap0 -> g_t
__global__ void hgc_post(int layer) {
    int n = blockIdx.x, d = threadIdx.x;
    __shared__ float red[128];
    float mv = g_mv[(size_t)n * DD + d];
    float ss2 = block_reduce_sum128(mv * mv, red);
    float nm = fmaxf(sqrtf(ss2), 1e-15f);
    float x = tanhf(nm) / nm * mv;
    float xn = tanhf(nm);
    if (xn > MAXN_F) { x *= MAXN_F / xn; xn = MAXN_F; }
    float y = g_hb[layer][d];
    float x2 = xn * xn;
    float y2 = block_reduce_sum128(y * y, red);
    float xy = block_reduce_sum128(x * y, red);
    float num = (1.f + 2.f * xy + y2) * x + (1.f - x2) * y;
    float den = 1.f + 2.f * xy + x2 * y2;
    den = (fabsf(den) < 1e-15f) ? 1e-15f : den;
    float hv2 = num / den;
    float s3 = block_reduce_sum128(hv2 * hv2, red);
    float nn = fmaxf(sqrtf(s3), 1e-15f);
    if (nn > MAXN_F) { hv2 *= MAXN_F / nn; nn = MAXN_F; }
    float sc3 = atanhf(fminf(nn, 1.f - 1e-7f)) / nn;
    g_t[(size_t)n * DD + d] = sc3 * hv2;
}

__global__ void hgc_agg(int which) {
    int n = blockIdx.x, d = threadIdx.x;
    __shared__ float red[128];
    int c = g_cnt[which][n];
    float acc = 0.f;
    for (int j = 0; j < c; j++) {
        acc += g_csrv[which][(size_t)n * CAP + j]
             * g_t[(size_t)g_csri[which][(size_t)n * CAP + j] * DD + d];
    }
    float ss = block_reduce_sum128(acc * acc, red);
    float nm = fmaxf(sqrtf(ss), 1e-15f);
    float x = tanhf(nm) / nm * acc;
    float xn = tanhf(nm);
    if (xn > MAXN_F) { x *= MAXN_F / xn; xn = MAXN_F; }
    float nrm = fmaxf(xn, 1e-15f);
    float u = atanhf(fminf(nrm, 1.f - 1e-7f)) / nrm * x;
    u = fmaxf(u, 0.f);
    float ss2 = block_reduce_sum128(u * u, red);
    float nm2 = fmaxf(sqrtf(ss2), 1e-15f);
    float x2 = tanhf(nm2) / nm2 * u;
    float xn2 = tanhf(nm2);
    if (xn2 > MAXN_F) x2 *= MAXN_F / xn2;
    g_h[(size_t)n * DD + d] = x2;
}

__global__ void hgc_out(const void* __restrict__ ent, int slot, float* __restrict__ out) {
    int n = blockIdx.x, d = threadIdx.x;
    __shared__ float red[128];
    float hv = g_h[(size_t)n * DD + d];
    float ss = block_reduce_sum128(hv * hv, red);
    float nrm = fmaxf(sqrtf(ss), 1e-15f);
    float u = atanhf(fminf(nrm, 1.f - 1e-7f)) / nrm * hv;
    out[(size_t)n * 256 + d] = ldin(ent, (size_t)n * DD + d, g_dt[slot]) + u;
}

extern "C" void kernel_launch(void* const* d_in, const int* in_sizes, int n_in,
                              void* d_out, int out_size, void* d_ws, size_t ws_size,
                              hipStream_t stream) {
    const void* ent_sr = d_in[0];
    const void* ent_tg = d_in[1];
    const void* rel_sr = d_in[2];
    const void* rel_tg = d_in[3];
    const void* adj_sr = d_in[4];
    const void* adj_tg = d_in[5];
    const void* rel_adj_sr = d_in[6];
    const void* rel_adj_tg = d_in[7];
    const void* gat_W     = d_in[8];
    const void* gat_a_src = d_in[9];
    const void* gat_a_dst = d_in[10];
    const void* Wq  = d_in[11];
    const void* Wk  = d_in[12];
    const void* Wv  = d_in[13];
    const void* Wfc = d_in[14];
    const void* ln_g = d_in[15];
    const void* ln_b = d_in[16];
    const void* hgc_W = d_in[17];
    const void* hgc_b = d_in[18];

    float* out  = (float*)d_out;
    float* out0 = out;
    float* out1 = out + (size_t)NN * 256;
    float* out2 = out + (size_t)2 * NN * 256;
    float* out3 = out + (size_t)3 * NN * 256;

    // device addresses of global buffers (symbol queries, not stream ops)
    float *p_seq, *p_hh, *p_qkv, *p_o, *p_fc, *p_u, *p_mv;
    float *p_Wgat, *p_Wqkv, *p_Wfc, *p_WhgcT;
    hipGetSymbolAddress((void**)&p_seq,   HIP_SYMBOL(g_seq));
    hipGetSymbolAddress((void**)&p_hh,    HIP_SYMBOL(g_hh));
    hipGetSymbolAddress((void**)&p_qkv,   HIP_SYMBOL(g_qkv));
    hipGetSymbolAddress((void**)&p_o,     HIP_SYMBOL(g_o));
    hipGetSymbolAddress((void**)&p_fc,    HIP_SYMBOL(g_fc));
    hipGetSymbolAddress((void**)&p_u,     HIP_SYMBOL(g_u));
    hipGetSymbolAddress((void**)&p_mv,    HIP_SYMBOL(g_mv));
    hipGetSymbolAddress((void**)&p_Wgat,  HIP_SYMBOL(g_Wgat));
    hipGetSymbolAddress((void**)&p_Wqkv,  HIP_SYMBOL(g_Wqkv));
    hipGetSymbolAddress((void**)&p_Wfc,   HIP_SYMBOL(g_Wfc));
    hipGetSymbolAddress((void**)&p_WhgcT, HIP_SYMBOL(g_WhgcT));

    P19 ptrs;
    for (int i = 0; i < 19; i++) ptrs.p[i] = d_in[i];
    detect_all<<<19, 256, 0, stream>>>(ptrs);
    prep_weights<<<128, 256, 0, stream>>>(gat_W, Wq, Wk, Wv, Wfc, hgc_W);

    build_csr<<<NN, 256, 0, stream>>>(adj_sr, 0, 4);
    build_csr<<<NN, 256, 0, stream>>>(adj_tg, 1, 5);

    rel_agg_kernel<<<NN, 128, 0, stream>>>(rel_adj_sr, rel_sr, 6, 2, out0, out2);
    rel_agg_kernel<<<NN, 128, 0, stream>>>(rel_adj_tg, rel_tg, 7, 3, out1, out3);

    for (int br = 0; br < 2; br++) {
        const void* ent = br ? ent_tg : ent_sr;
        float* outc = br ? out1 : out0;
        copy_ent_seq<<<NN, 128, 0, stream>>>(ent, br);
        for (int layer = 0; layer < 2; layer++) {
            gemm64<<<dim3(4, 94), 256, 0, stream>>>(p_seq + layer * 128, 384,
                                                    p_Wgat + layer * 32768, 256,
                                                    p_hh, 256, NN, 128);
            gat_scores<<<NN, 256, 0, stream>>>(layer, gat_a_src, gat_a_dst);
            gat_attn<<<NN, 128, 0, stream>>>(br, layer);
        }
        gemm64<<<dim3(12, 282), 256, 0, stream>>>(p_seq, 128, p_Wqkv, 768,
                                                  p_qkv, 768, NN * 3, 128);
        mha_attn<<<NN, 256, 0, stream>>>();
        gemm64<<<dim3(2, 282), 256, 0, stream>>>(p_o, 256, p_Wfc, 128,
                                                 p_fc, 128, NN * 3, 256);
        mha_out<<<NN, 128, 0, stream>>>(ln_g, ln_b, outc);
    }

    hgc_bias<<<2, 128, 0, stream>>>(hgc_b);
    for (int br = 0; br < 2; br++) {
        const void* ent = br ? ent_tg : ent_sr;
        float* outc = br ? out3 : out2;
        hgc_init<<<NN, 128, 0, stream>>>(ent, br);
        for (int layer = 0; layer < 2; layer++) {
            hgc_log<<<NN, 128, 0, stream>>>();
            gemm64<<<dim3(2, 94), 256, 0, stream>>>(p_u, 128, p_WhgcT + layer * 16384, 128,
                                                    p_mv, 128, NN, 128);
            hgc_post<<<NN, 128, 0, stream>>>(layer);
            hgc_agg<<<NN, 128, 0, stream>>>(br);
        }
        hgc_out<<<NN, 128, 0, stream>>>(ent, br, outc);
    }
}

// Round 6
// 1054.296 us; speedup vs baseline: 2.4170x; 1.1045x over previous
//
#include <hip/hip_runtime.h>
#include <hip/hip_bf16.h>
#include <math.h>

#define NN   6000
#define N2   12000
#define DD   128
#define RR   1000
#define CAP  96
#define CAPR 48
#define MAXN_F 0.996f

// ---------------- module-global scratch ----------------
__device__ int      g_dt[19];
__device__ unsigned g_csri[N2 * CAP];
__device__ float    g_csrv[N2 * CAP];
__device__ int      g_cnt[N2];
__device__ float    g_seq[N2 * 3 * DD];       // [gn][l][d]
__device__ float    g_hh[N2 * 256];           // [gn][h*128+e]
__device__ float    g_es[2][N2];
__device__ float    g_ed[2][N2];
__device__ float    g_qkv[(size_t)N2 * 3 * 768];
__device__ float    g_o[(size_t)N2 * 3 * 256];
__device__ float    g_fc[N2 * 3 * DD];
__device__ float    g_u[N2 * DD];             // tangent vectors
__device__ float    g_t[N2 * DD];
__device__ float    g_hb[2][DD];
__device__ float    g_hb2[2];
// packed f32 weights
__device__ float    g_Wgat[2][DD * 256];      // [l][d][h*128+e]
__device__ float    g_Wqkv[DD * 768];
__device__ float    g_Wfc[256 * DD];
__device__ float    g_Whgc[2][DD * DD];       // [l][d][j]

__device__ __forceinline__ float ldin(const void* p, size_t i, int bf) {
    if (bf) return __uint_as_float(((unsigned)((const unsigned short*)p)[i]) << 16);
    return ((const float*)p)[i];
}

struct P19 { const void* p[19]; };

__global__ void detect_all(P19 ptrs) {
    const int sizes[19] = {768000,768000,128000,128000,36000000,36000000,6000000,6000000,
                           65536,512,512,32768,32768,32768,32768,128,128,32768,256};
    int slot = blockIdx.x;
    const unsigned* p = (const unsigned*)ptrs.p[slot];
    __shared__ int votes[2];
    if (threadIdx.x == 0) { votes[0] = 0; votes[1] = 0; }
    __syncthreads();
    int nwords = sizes[slot] / 2;
    if (nwords > 0) {
        int nsamp = nwords < 4096 ? nwords : 4096;
        int stride = nwords / nsamp; if (stride < 1) stride = 1;
        for (int s = threadIdx.x; s < nsamp; s += blockDim.x) {
            unsigned lo = p[(size_t)s * stride] & 0xFFFFu;
            if (lo) {
                unsigned e = (lo >> 7) & 0xFFu;
                if (e >= 100u && e <= 140u) atomicAdd(&votes[1], 1);
                else                        atomicAdd(&votes[0], 1);
            }
        }
    }
    __syncthreads();
    if (threadIdx.x == 0) g_dt[slot] = (votes[1] > votes[0]) ? 1 : 0;
}

__global__ void prep_weights(const void* gatW, const void* Wq, const void* Wk, const void* Wv,
                             const void* Wfc, const void* hgcW) {
    int stride = gridDim.x * blockDim.x;
    int base = blockIdx.x * blockDim.x + threadIdx.x;
    const int b8 = g_dt[8], b11 = g_dt[11], b12 = g_dt[12], b13 = g_dt[13],
              b14 = g_dt[14], b17 = g_dt[17];
    for (int i = base; i < 65536; i += stride) {
        int e = i & 127, d = (i >> 7) & 127, h = (i >> 14) & 1, l = (i >> 15) & 1;
        g_Wgat[l][(d << 8) + (h << 7) + e] = ldin(gatW, i, b8);
    }
    for (int i = base; i < 32768; i += stride) {
        int d = i >> 8, e = i & 255;
        g_Wqkv[d * 768 + e]       = ldin(Wq, i, b11);
        g_Wqkv[d * 768 + 256 + e] = ldin(Wk, i, b12);
        g_Wqkv[d * 768 + 512 + e] = ldin(Wv, i, b13);
    }
    for (int i = base; i < 32768; i += stride) g_Wfc[i] = ldin(Wfc, i, b14);
    for (int i = base; i < 32768; i += stride) g_Whgc[0][i] = ldin(hgcW, i, b17); // [l][d][j] flat
}

__device__ __forceinline__ float block_reduce_sum128(float v, float* red) {
    int d = threadIdx.x;
    red[d] = v; __syncthreads();
    for (int s = 64; s > 0; s >>= 1) {
        if (d < s) red[d] += red[d + s];
        __syncthreads();
    }
    float r = red[0]; __syncthreads();
    return r;
}
__device__ __forceinline__ float block_reduce_max128(float v, float* red) {
    int d = threadIdx.x;
    red[d] = v; __syncthreads();
    for (int s = 64; s > 0; s >>= 1) {
        if (d < s) red[d] = fmaxf(red[d], red[d + s]);
        __syncthreads();
    }
    float r = red[0]; __syncthreads();
    return r;
}

// ---------------- 128x128 tile GEMM, 8x8 micro-tile, f32 ----------------
// grid (N/128, ceil(M/128)), 256 threads. K multiple of 32, N multiple of 128.
__global__ __launch_bounds__(256) void gemm128(const float* __restrict__ A, int lda,
                                               const float* __restrict__ B, int ldb,
                                               float* __restrict__ C, int ldc,
                                               int M, int K) {
    __shared__ float As[32][132];   // [k][m], 528 B row stride (16B-aligned)
    __shared__ float Bs[32][132];   // [k][n]
    int bm = blockIdx.y * 128, bn = blockIdx.x * 128;
    int tid = threadIdx.x;
    int tm = tid >> 4, tn = tid & 15;
    float acc[8][8] = {};
    for (int k0 = 0; k0 < K; k0 += 32) {
        #pragma unroll
        for (int i = 0; i < 4; i++) {
            int fi = tid + i * 256;          // A: 128 rows x 8 float4
            int m = fi >> 3, kk = fi & 7;
            float4 a = {0.f, 0.f, 0.f, 0.f};
            if (bm + m < M) a = *(const float4*)(A + (size_t)(bm + m) * lda + k0 + kk * 4);
            As[kk * 4 + 0][m] = a.x; As[kk * 4 + 1][m] = a.y;
            As[kk * 4 + 2][m] = a.z; As[kk * 4 + 3][m] = a.w;
            int r = fi >> 5, cg = fi & 31;   // B: 32 rows x 32 float4
            *(float4*)&Bs[r][cg * 4] = *(const float4*)(B + (size_t)(k0 + r) * ldb + bn + cg * 4);
        }
        __syncthreads();
        #pragma unroll
        for (int k = 0; k < 32; k++) {
            float4 a0 = *(float4*)&As[k][tm * 8];
            float4 a1 = *(float4*)&As[k][tm * 8 + 4];
            float4 b0 = *(float4*)&Bs[k][tn * 8];
            float4 b1 = *(float4*)&Bs[k][tn * 8 + 4];
            float av[8] = {a0.x, a0.y, a0.z, a0.w, a1.x, a1.y, a1.z, a1.w};
            float bv[8] = {b0.x, b0.y, b0.z, b0.w, b1.x, b1.y, b1.z, b1.w};
            #pragma unroll
            for (int i = 0; i < 8; i++)
                #pragma unroll
                for (int j = 0; j < 8; j++)
                    acc[i][j] = fmaf(av[i], bv[j], acc[i][j]);
        }
        __syncthreads();
    }
    #pragma unroll
    for (int i = 0; i < 8; i++) {
        int m = bm + tm * 8 + i;
        if (m < M) {
            float4 c0 = {acc[i][0], acc[i][1], acc[i][2], acc[i][3]};
            float4 c1 = {acc[i][4], acc[i][5], acc[i][6], acc[i][7]};
            *(float4*)(C + (size_t)m * ldc + bn + tn * 8)     = c0;
            *(float4*)(C + (size_t)m * ldc + bn + tn * 8 + 4) = c1;
        }
    }
}

// ---------------- CSR build (merged branches, vectorized scan) ----------------
__global__ void build_csr(const void* __restrict__ A0, const void* __restrict__ A1) {
    int n = blockIdx.x;
    int which = n >= NN ? 1 : 0;
    const void* A = which ? A1 : A0;
    const int bf = g_dt[4 + which];
    int row = n - which * NN;
    __shared__ int c;
    if (threadIdx.x == 0) c = 0;
    __syncthreads();
    if (bf) {
        const uint2* p = (const uint2*)((const unsigned short*)A + (size_t)row * NN);
        for (int i = threadIdx.x; i < NN / 4; i += blockDim.x) {
            uint2 w = p[i];
            unsigned v[4] = {w.x & 0xFFFFu, w.x >> 16, w.y & 0xFFFFu, w.y >> 16};
            #pragma unroll
            for (int r = 0; r < 4; r++) {
                unsigned b = v[r];
                if (b && !(b & 0x8000u)) {
                    int q = atomicAdd(&c, 1);
                    if (q < CAP) {
                        g_csri[(size_t)n * CAP + q] = (unsigned)(i * 4 + r);
                        g_csrv[(size_t)n * CAP + q] = __uint_as_float(b << 16);
                    }
                }
            }
        }
    } else {
        const float2* p = (const float2*)((const float*)A + (size_t)row * NN);
        for (int i = threadIdx.x; i < NN / 2; i += blockDim.x) {
            float2 w = p[i];
            if (w.x > 0.f) { int q = atomicAdd(&c, 1); if (q < CAP) {
                g_csri[(size_t)n * CAP + q] = (unsigned)(i * 2); g_csrv[(size_t)n * CAP + q] = w.x; } }
            if (w.y > 0.f) { int q = atomicAdd(&c, 1); if (q < CAP) {
                g_csri[(size_t)n * CAP + q] = (unsigned)(i * 2 + 1); g_csrv[(size_t)n * CAP + q] = w.y; } }
        }
    }
    __syncthreads();
    if (threadIdx.x == 0) g_cnt[n] = min(c, CAP);
}

// ---------------- Relation aggregator (merged) ----------------
__global__ void rel_agg_kernel(const void* __restrict__ ra0, const void* __restrict__ ra1,
                               const void* __restrict__ re0, const void* __restrict__ re1,
                               float* __restrict__ out) {
    int n = blockIdx.x, d = threadIdx.x;
    int which = n >= NN ? 1 : 0;
    const void* radj = which ? ra1 : ra0;
    const void* rel  = which ? re1 : re0;
    const int bfa = g_dt[6 + which], bfr = g_dt[2 + which];
    int row = n - which * NN;
    __shared__ int list[CAPR];
    __shared__ int cs;
    if (d == 0) cs = 0;
    __syncthreads();
    for (int m = d; m < RR; m += 128) {
        float a = ldin(radj, (size_t)row * RR + m, bfa);
        if (a > 0.f) { int p = atomicAdd(&cs, 1); if (p < CAPR) list[p] = m; }
    }
    __syncthreads();
    int c = min(cs, CAPR);
    float acc = 0.f;
    for (int j = 0; j < c; j++) acc += ldin(rel, (size_t)list[j] * DD + d, bfr);
    float r = c ? acc / (float)c : 0.f;
    out[(size_t)n * 256 + 128 + d] = r;                       // chunks 0/1
    out[(size_t)(2 * NN + n) * 256 + 128 + d] = r;            // chunks 2/3
}

// ---------------- GAT ----------------
__global__ void copy_ent_seq(const void* __restrict__ e0, const void* __restrict__ e1) {
    int n = blockIdx.x, d = threadIdx.x;
    int which = n >= NN ? 1 : 0;
    g_seq[(size_t)n * 384 + d] = ldin(which ? e1 : e0, (size_t)(n - which * NN) * DD + d, g_dt[which]);
}

__global__ __launch_bounds__(256) void gat_scores(int layer, const void* __restrict__ a_src,
                                                  const void* __restrict__ a_dst) {
    int n = blockIdx.x, tid = threadIdx.x;
    int h = tid >> 7, e = tid & 127;
    const int bfs = g_dt[9], bfd = g_dt[10];
    __shared__ float red[256];
    float hv = g_hh[(size_t)n * 256 + tid];
    size_t abase = ((size_t)layer * 2 + h) * DD;
    red[tid] = hv * ldin(a_src, abase + e, bfs); __syncthreads();
    for (int s = 64; s > 0; s >>= 1) { if ((tid & 127) < s) red[tid] += red[tid + s]; __syncthreads(); }
    if ((tid & 127) == 0) g_es[h][n] = red[tid];
    __syncthreads();
    red[tid] = hv * ldin(a_dst, abase + e, bfd); __syncthreads();
    for (int s = 64; s > 0; s >>= 1) { if ((tid & 127) < s) red[tid] += red[tid + s]; __syncthreads(); }
    if ((tid & 127) == 0) g_ed[h][n] = red[tid];
}

__global__ void gat_attn(int layer) {
    int n = blockIdx.x, d = threadIdx.x;   // 128 threads
    int which = n >= NN ? 1 : 0;
    int c = g_cnt[n];                       // c <= CAP=96 < 128
    __shared__ float w0s[CAP], w1s[CAP];
    __shared__ int   idxs[CAP];
    __shared__ float red[128];
    float es0 = g_es[0][n], es1 = g_es[1][n];
    float e0 = -1e30f, e1 = -1e30f;
    if (d < c) {
        int gI = (int)g_csri[(size_t)n * CAP + d] + which * NN;
        idxs[d] = gI;
        e0 = es0 + g_ed[0][gI]; e0 = e0 > 0.f ? e0 : 0.2f * e0;
        e1 = es1 + g_ed[1][gI]; e1 = e1 > 0.f ? e1 : 0.2f * e1;
    }
    float m0 = block_reduce_max128(e0, red);
    float m1 = block_reduce_max128(e1, red);
    float w0 = (d < c) ? expf(e0 - m0) : 0.f;
    float w1 = (d < c) ? expf(e1 - m1) : 0.f;
    float s0 = block_reduce_sum128(w0, red);
    float s1 = block_reduce_sum128(w1, red);
    if (d < c) { w0s[d] = w0 / fmaxf(s0, 1e-30f); w1s[d] = w1 / fmaxf(s1, 1e-30f); }
    __syncthreads();
    float a0 = 0.f, a1 = 0.f;
    for (int j = 0; j < c; j++) {
        size_t base = (size_t)idxs[j] * 256;
        a0 = fmaf(w0s[j], g_hh[base + d], a0);
        a1 = fmaf(w1s[j], g_hh[base + 128 + d], a1);
    }
    float o = (c > 0) ? 0.5f * (a0 + a1) : 0.f;
    o = o > 0.f ? o : expm1f(o);            // elu
    float ss = block_reduce_sum128(o * o, red);
    float r = o / fmaxf(sqrtf(ss), 1e-12f);
    g_seq[(size_t)n * 384 + (layer + 1) * 128 + d] = r;
}

// ---------------- MHA ----------------
__global__ __launch_bounds__(256) void mha_attn() {
    int n = blockIdx.x, tid = threadIdx.x;
    __shared__ float qs[3][256], ks[3][256], vs[3][256];
    __shared__ float att[2][3][3];
    for (int t = tid; t < 768; t += 256) {
        int l = t >> 8, e = t & 255;
        size_t base = (size_t)(n * 3 + l) * 768;
        qs[l][e] = g_qkv[base + e];
        ks[l][e] = g_qkv[base + 256 + e];
        vs[l][e] = g_qkv[base + 512 + e];
    }
    __syncthreads();
    if (tid < 18) {
        int h = tid / 9, lm = tid % 9, l = lm / 3, m = lm % 3;
        float acc = 0.f;
        for (int d = 0; d < 128; d++) acc += qs[l][h * 128 + d] * ks[m][h * 128 + d];
        att[h][l][m] = acc * 0.08838834764831845f;
    }
    __syncthreads();
    if (tid < 6) {
        int h = tid / 3, l = tid % 3;
        float mx = fmaxf(att[h][l][0], fmaxf(att[h][l][1], att[h][l][2]));
        float e0 = expf(att[h][l][0] - mx), e1 = expf(att[h][l][1] - mx), e2 = expf(att[h][l][2] - mx);
        float s = fmaxf(e0 + e1 + e2, 1e-30f);
        att[h][l][0] = e0 / s; att[h][l][1] = e1 / s; att[h][l][2] = e2 / s;
    }
    __syncthreads();
    for (int t = tid; t < 768; t += 256) {
        int l = t >> 8, e = t & 255, h = e >> 7;
        g_o[(size_t)(n * 3 + l) * 256 + e] =
            att[h][l][0] * vs[0][e] + att[h][l][1] * vs[1][e] + att[h][l][2] * vs[2][e];
    }
}

__global__ void mha_out(const void* __restrict__ g, const void* __restrict__ b,
                        float* __restrict__ out) {
    int n = blockIdx.x, d = threadIdx.x;
    const int bg = g_dt[15], bb = g_dt[16];
    __shared__ float red[128];
    float ool[3], mu[3], rstd[3];
    #pragma unroll
    for (int l = 0; l < 3; l++)
        ool[l] = g_fc[(size_t)(n * 3 + l) * 128 + d] + g_seq[(size_t)(n * 3 + l) * 128 + d];
    #pragma unroll
    for (int l = 0; l < 3; l++) {
        float s  = block_reduce_sum128(ool[l], red);
        float ss = block_reduce_sum128(ool[l] * ool[l], red);
        mu[l] = s / 128.f;
        rstd[l] = rsqrtf(ss / 128.f - mu[l] * mu[l] + 1e-6f);
    }
    float acc = 0.f;
    #pragma unroll
    for (int l = 0; l < 3; l++) acc += (ool[l] - mu[l]) * rstd[l];
    out[(size_t)n * 256 + d] = ldin(g, d, bg) * (acc / 3.f) + ldin(b, d, bb);
}

// ---------------- Hyperbolic GCN (fused tangent-space formulation) ----------------
__global__ void hgc_bias(const void* __restrict__ hgc_b) {
    int i = blockIdx.x, d = threadIdx.x;
    __shared__ float red[128];
    float bv = ldin(hgc_b, (size_t)i * DD + d, g_dt[18]);
    float ss = block_reduce_sum128(bv * bv, red);
    float nrm = fmaxf(sqrtf(ss), 1e-15f);
    float t = tanhf(nrm);
    float v = t / nrm * bv;
    float vn = t;
    if (t > MAXN_F) { v *= MAXN_F / t; vn = MAXN_F; }
    g_hb[i][d] = v;
    if (d == 0) g_hb2[i] = vn * vn;
}

// u(input) -> mv = u@W.T -> proj(expmap0) -> mobius_add(.,hb) -> proj -> logmap0 -> g_t
__global__ void hgc_linear(const void* __restrict__ e0, const void* __restrict__ e1, int layer) {
    int n = blockIdx.x, d = threadIdx.x;
    __shared__ float red[128];
    __shared__ float u[128];
    float uv;
    if (layer == 0) {
        int which = n >= NN ? 1 : 0;
        float x = ldin(which ? e1 : e0, (size_t)(n - which * NN) * DD + d, g_dt[which]);
        float ss = block_reduce_sum128(x * x, red);
        float nrm = fmaxf(sqrtf(ss), 1e-15f);
        float t = tanhf(nrm);
        float scale = t / nrm;
        float hn = t;
        if (t > MAXN_F) { scale *= MAXN_F / t; hn = MAXN_F; }
        uv = atanhf(fminf(hn, 1.f - 1e-7f)) / fmaxf(hn, 1e-15f) * (scale * x);
    } else {
        uv = g_u[(size_t)n * DD + d];
    }
    u[d] = uv; __syncthreads();
    const float* W = &g_Whgc[layer][d * DD];
    float mv = 0.f;
    #pragma unroll
    for (int j = 0; j < DD; j += 4) {
        float4 w = *(const float4*)(W + j);
        float4 uu = *(const float4*)(&u[j]);
        mv = fmaf(w.x, uu.x, fmaf(w.y, uu.y, fmaf(w.z, uu.z, fmaf(w.w, uu.w, mv))));
    }
    float ss2 = block_reduce_sum128(mv * mv, red);
    float nm = fmaxf(sqrtf(ss2), 1e-15f);
    float t2 = tanhf(nm);
    float x = t2 / nm * mv;
    float xn = t2;
    if (t2 > MAXN_F) { x *= MAXN_F / t2; xn = MAXN_F; }
    // mobius_add(x, hb)
    float y = g_hb[layer][d];
    float x2 = xn * xn;
    float y2 = g_hb2[layer];
    float xy = block_reduce_sum128(x * y, red);
    float num = (1.f + 2.f * xy + y2) * x + (1.f - x2) * y;
    float den = 1.f + 2.f * xy + x2 * y2;
    den = (fabsf(den) < 1e-15f) ? 1e-15f : den;
    float hv2 = num / den;
    float s3 = block_reduce_sum128(hv2 * hv2, red);
    float nn = fmaxf(sqrtf(s3), 1e-15f);
    if (nn > MAXN_F) { hv2 *= MAXN_F / nn; nn = MAXN_F; }
    float sc3 = atanhf(fminf(nn, 1.f - 1e-7f)) / nn;
    g_t[(size_t)n * DD + d] = sc3 * hv2;
}

// SpMM over CSR + expmap/relu/expmap, emitting tangent vector (logmap0 of result)
__global__ void hgc_agg(int layer, const void* __restrict__ e0, const void* __restrict__ e1,
                        float* __restrict__ out) {
    int n = blockIdx.x, d = threadIdx.x;
    int which = n >= NN ? 1 : 0;
    __shared__ float red[128];
    int c = g_cnt[n];
    float acc = 0.f;
    for (int j = 0; j < c; j++) {
        acc = fmaf(g_csrv[(size_t)n * CAP + j],
                   g_t[((size_t)g_csri[(size_t)n * CAP + j] + which * NN) * DD + d], acc);
    }
    float ss = block_reduce_sum128(acc * acc, red);
    float nm = fmaxf(sqrtf(ss), 1e-15f);
    float t = tanhf(nm);
    float x = t / nm * acc;
    float xn = t;
    if (t > MAXN_F) { x *= MAXN_F / t; xn = MAXN_F; }
    float u = atanhf(fminf(xn, 1.f - 1e-7f)) / fmaxf(xn, 1e-15f) * x;
    u = fmaxf(u, 0.f);                       // relu in tangent space
    float ss2 = block_reduce_sum128(u * u, red);
    float nm2 = fmaxf(sqrtf(ss2), 1e-15f);
    float t2 = tanhf(nm2);
    float x2 = t2 / nm2 * u;
    float xn2 = t2;
    if (t2 > MAXN_F) { x2 *= MAXN_F / t2; xn2 = MAXN_F; }
    float u3 = atanhf(fminf(xn2, 1.f - 1e-7f)) / fmaxf(xn2, 1e-15f) * x2;  // logmap0(result)
    if (layer == 0) {
        g_u[(size_t)n * DD + d] = u3;
    } else {
        float ev = ldin(which ? e1 : e0, (size_t)(n - which * NN) * DD + d, g_dt[which]);
        out[(size_t)(2 * NN + n) * 256 + d] = ev + u3;
    }
}

extern "C" void kernel_launch(void* const* d_in, const int* in_sizes, int n_in,
                              void* d_out, int out_size, void* d_ws, size_t ws_size,
                              hipStream_t stream) {
    const void* ent_sr = d_in[0];
    const void* ent_tg = d_in[1];
    const void* rel_sr = d_in[2];
    const void* rel_tg = d_in[3];
    const void* adj_sr = d_in[4];
    const void* adj_tg = d_in[5];
    const void* rel_adj_sr = d_in[6];
    const void* rel_adj_tg = d_in[7];
    const void* gat_W     = d_in[8];
    const void* gat_a_src = d_in[9];
    const void* gat_a_dst = d_in[10];
    const void* Wq  = d_in[11];
    const void* Wk  = d_in[12];
    const void* Wv  = d_in[13];
    const void* Wfc = d_in[14];
    const void* ln_g = d_in[15];
    const void* ln_b = d_in[16];
    const void* hgc_W = d_in[17];
    const void* hgc_b = d_in[18];

    float* out = (float*)d_out;

    float *p_seq, *p_hh, *p_qkv, *p_o, *p_fc, *p_Wgat, *p_Wqkv, *p_Wfc;
    hipGetSymbolAddress((void**)&p_seq,  HIP_SYMBOL(g_seq));
    hipGetSymbolAddress((void**)&p_hh,   HIP_SYMBOL(g_hh));
    hipGetSymbolAddress((void**)&p_qkv,  HIP_SYMBOL(g_qkv));
    hipGetSymbolAddress((void**)&p_o,    HIP_SYMBOL(g_o));
    hipGetSymbolAddress((void**)&p_fc,   HIP_SYMBOL(g_fc));
    hipGetSymbolAddress((void**)&p_Wgat, HIP_SYMBOL(g_Wgat));
    hipGetSymbolAddress((void**)&p_Wqkv, HIP_SYMBOL(g_Wqkv));
    hipGetSymbolAddress((void**)&p_Wfc,  HIP_SYMBOL(g_Wfc));

    P19 ptrs;
    for (int i = 0; i < 19; i++) ptrs.p[i] = d_in[i];
    detect_all<<<19, 256, 0, stream>>>(ptrs);
    prep_weights<<<128, 256, 0, stream>>>(gat_W, Wq, Wk, Wv, Wfc, hgc_W);

    build_csr<<<N2, 256, 0, stream>>>(adj_sr, adj_tg);
    rel_agg_kernel<<<N2, 128, 0, stream>>>(rel_adj_sr, rel_adj_tg, rel_sr, rel_tg, out);

    copy_ent_seq<<<N2, 128, 0, stream>>>(ent_sr, ent_tg);
    for (int layer = 0; layer < 2; layer++) {
        // hh = seq[:,layer,:] @ Wgat[layer]   [12000 x 128] @ [128 x 256]
        gemm128<<<dim3(2, 94), 256, 0, stream>>>(p_seq + layer * 128, 384,
                                                 p_Wgat + layer * 32768, 256,
                                                 p_hh, 256, N2, 128);
        gat_scores<<<N2, 256, 0, stream>>>(layer, gat_a_src, gat_a_dst);
        gat_attn<<<N2, 128, 0, stream>>>(layer);
    }
    // qkv = seq @ Wqkv   [36000 x 128] @ [128 x 768]
    gemm128<<<dim3(6, 282), 256, 0, stream>>>(p_seq, 128, p_Wqkv, 768, p_qkv, 768, N2 * 3, 128);
    mha_attn<<<N2, 256, 0, stream>>>();
    // fc = o @ Wfc       [36000 x 256] @ [256 x 128]
    gemm128<<<dim3(1, 282), 256, 0, stream>>>(p_o, 256, p_Wfc, 128, p_fc, 128, N2 * 3, 256);
    mha_out<<<N2, 128, 0, stream>>>(ln_g, ln_b, out);

    hgc_bias<<<2, 128, 0, stream>>>(hgc_b);
    for (int layer = 0; layer < 2; layer++) {
        hgc_linear<<<N2, 128, 0, stream>>>(ent_sr, ent_tg, layer);
        hgc_agg<<<N2, 128, 0, stream>>>(layer, ent_sr, ent_tg, out);
    }
}

// Round 7
// 889.866 us; speedup vs baseline: 2.8636x; 1.1848x over previous
//
#include <hip/hip_runtime.h>
#include <hip/hip_bf16.h>
#include <math.h>

#define NN   6000
#define N2   12000
#define DD   128
#define RR   1000
#define CAP  96
#define CAPR 48
#define MAXN_F 0.996f

typedef short  bf16x8 __attribute__((ext_vector_type(8)));
typedef float  f32x4  __attribute__((ext_vector_type(4)));

// ---------------- module-global scratch ----------------
__device__ int      g_dt[19];
__device__ unsigned g_csri[N2 * CAP];
__device__ float    g_csrv[N2 * CAP];
__device__ int      g_cnt[N2];
__device__ float    g_seq[N2 * 3 * DD];          // f32 [n][l][d]
__device__ unsigned short g_seqb[N2 * 3 * DD];   // bf16 mirror
__device__ unsigned short g_hhb[N2 * 256];       // bf16 GAT projections
__device__ float    g_es[2][N2];
__device__ float    g_ed[2][N2];
__device__ unsigned short g_qkvb[(size_t)N2 * 3 * 768];
__device__ unsigned short g_ob[(size_t)N2 * 3 * 256];
__device__ float    g_fc[N2 * 3 * DD];
__device__ float    g_u[N2 * DD];
__device__ float    g_t[N2 * DD];
__device__ float    g_hb[2][DD];
__device__ float    g_hb2[2];
// packed weights: B^T bf16 rows (n-major, K contiguous)
__device__ unsigned short g_WgatT[2][256 * DD];  // [l][n=h*128+e][k=d]
__device__ unsigned short g_WqkvT[768 * DD];     // [n][k]
__device__ unsigned short g_WfcT[DD * 256];      // [n=dd][k=e]
__device__ float    g_Whgc[2][DD * DD];          // f32 [l][d][j]

__device__ __forceinline__ float ldin(const void* p, size_t i, int bf) {
    if (bf) return __uint_as_float(((unsigned)((const unsigned short*)p)[i]) << 16);
    return ((const float*)p)[i];
}
__device__ __forceinline__ unsigned short f2b(float f) {   // RN-even f32->bf16 bits
    unsigned u = __float_as_uint(f);
    u += 0x7FFFu + ((u >> 16) & 1u);
    return (unsigned short)(u >> 16);
}
__device__ __forceinline__ float b2f(unsigned short b) {
    return __uint_as_float(((unsigned)b) << 16);
}

struct P19 { const void* p[19]; };

__global__ void detect_all(P19 ptrs) {
    const int sizes[19] = {768000,768000,128000,128000,36000000,36000000,6000000,6000000,
                           65536,512,512,32768,32768,32768,32768,128,128,32768,256};
    int slot = blockIdx.x;
    const unsigned* p = (const unsigned*)ptrs.p[slot];
    __shared__ int votes[2];
    if (threadIdx.x == 0) { votes[0] = 0; votes[1] = 0; }
    __syncthreads();
    int nwords = sizes[slot] / 2;
    if (nwords > 0) {
        int nsamp = nwords < 4096 ? nwords : 4096;
        int stride = nwords / nsamp; if (stride < 1) stride = 1;
        for (int s = threadIdx.x; s < nsamp; s += blockDim.x) {
            unsigned lo = p[(size_t)s * stride] & 0xFFFFu;
            if (lo) {
                unsigned e = (lo >> 7) & 0xFFu;
                if (e >= 100u && e <= 140u) atomicAdd(&votes[1], 1);
                else                        atomicAdd(&votes[0], 1);
            }
        }
    }
    __syncthreads();
    if (threadIdx.x == 0) g_dt[slot] = (votes[1] > votes[0]) ? 1 : 0;
}

__global__ void prep_weights(const void* gatW, const void* Wq, const void* Wk, const void* Wv,
                             const void* Wfc, const void* hgcW) {
    int stride = gridDim.x * blockDim.x;
    int base = blockIdx.x * blockDim.x + threadIdx.x;
    const int b8 = g_dt[8], b11 = g_dt[11], b12 = g_dt[12], b13 = g_dt[13],
              b14 = g_dt[14], b17 = g_dt[17];
    for (int i = base; i < 65536; i += stride) {          // gat_W [l][h][d][e]
        int e = i & 127, d = (i >> 7) & 127, h = (i >> 14) & 1, l = (i >> 15) & 1;
        g_WgatT[l][(h * 128 + e) * DD + d] = f2b(ldin(gatW, i, b8));
    }
    for (int i = base; i < 32768; i += stride) {          // Wq/Wk/Wv [d][e]
        int d = i >> 8, e = i & 255;
        g_WqkvT[(size_t)e * DD + d]         = f2b(ldin(Wq, i, b11));
        g_WqkvT[(size_t)(256 + e) * DD + d] = f2b(ldin(Wk, i, b12));
        g_WqkvT[(size_t)(512 + e) * DD + d] = f2b(ldin(Wv, i, b13));
    }
    for (int i = base; i < 32768; i += stride) {          // Wfc [e][dd]
        int e = i >> 7, dd = i & 127;
        g_WfcT[dd * 256 + e] = f2b(ldin(Wfc, i, b14));
    }
    for (int i = base; i < 32768; i += stride) g_Whgc[0][i] = ldin(hgcW, i, b17);
}

__device__ __forceinline__ float block_reduce_sum128(float v, float* red) {
    int d = threadIdx.x;
    red[d] = v; __syncthreads();
    for (int s = 64; s > 0; s >>= 1) {
        if (d < s) red[d] += red[d + s];
        __syncthreads();
    }
    float r = red[0]; __syncthreads();
    return r;
}
__device__ __forceinline__ float block_reduce_max128(float v, float* red) {
    int d = threadIdx.x;
    red[d] = v; __syncthreads();
    for (int s = 64; s > 0; s >>= 1) {
        if (d < s) red[d] = fmaxf(red[d], red[d + s]);
        __syncthreads();
    }
    float r = red[0]; __syncthreads();
    return r;
}

// ---------------- MFMA bf16 GEMM: C[M x N] = A[M x K] @ B  (B given as B^T[N x K]) ----------
// grid (N/128, ceil(M/128)), 256 threads (4 waves). K multiple of 128.
// LDS layout: cell (c, r) = 8 bf16 at offset (c*128 + r)*8 ushorts; c = k-chunk (k/8), r = row.
// Fragment reads: lane(l) of wave w reads cell (s*4 + (l>>4), tile*16 + (l&15)) -> conflict-free.
template<bool OUT_BF16>
__global__ __launch_bounds__(256) void gemm_mfma(const unsigned short* __restrict__ A, int lda,
                                                 const unsigned short* __restrict__ Bt, int ldb,
                                                 void* __restrict__ C, int ldc, int M, int K) {
    __shared__ __align__(16) unsigned short As[16 * 128 * 8];  // 32 KB
    __shared__ __align__(16) unsigned short Bs[16 * 128 * 8];  // 32 KB
    int bm = blockIdx.y * 128, bn = blockIdx.x * 128;
    int tid = threadIdx.x;
    int lane = tid & 63, w = tid >> 6;
    int q = lane >> 4, ln = lane & 15;
    f32x4 acc[8][2] = {};
    for (int k0 = 0; k0 < K; k0 += 128) {
        if (k0 > 0) __syncthreads();
        #pragma unroll
        for (int i = 0; i < 8; i++) {
            int combo = w * 8 + i;            // 0..31 -> (c, half)
            int c = combo >> 1, half = combo & 1;
            int r = half * 64 + lane;
            int gm = bm + r; if (gm >= M) gm = M - 1;
            *(uint4*)&As[(c * 128 + r) * 8] =
                *(const uint4*)(A + (size_t)gm * lda + k0 + c * 8);
            *(uint4*)&Bs[(c * 128 + r) * 8] =
                *(const uint4*)(Bt + (size_t)(bn + r) * ldb + k0 + c * 8);
        }
        __syncthreads();
        #pragma unroll
        for (int s = 0; s < 4; s++) {
            bf16x8 bf0 = *(const bf16x8*)&Bs[((s * 4 + q) * 128 + w * 32 + ln) * 8];
            bf16x8 bf1 = *(const bf16x8*)&Bs[((s * 4 + q) * 128 + w * 32 + 16 + ln) * 8];
            #pragma unroll
            for (int mt = 0; mt < 8; mt++) {
                bf16x8 af = *(const bf16x8*)&As[((s * 4 + q) * 128 + mt * 16 + ln) * 8];
                acc[mt][0] = __builtin_amdgcn_mfma_f32_16x16x32_bf16(af, bf0, acc[mt][0], 0, 0, 0);
                acc[mt][1] = __builtin_amdgcn_mfma_f32_16x16x32_bf16(af, bf1, acc[mt][1], 0, 0, 0);
            }
        }
    }
    #pragma unroll
    for (int mt = 0; mt < 8; mt++) {
        #pragma unroll
        for (int nt = 0; nt < 2; nt++) {
            int gcol = bn + w * 32 + nt * 16 + ln;
            #pragma unroll
            for (int r = 0; r < 4; r++) {
                int grow = bm + mt * 16 + q * 4 + r;
                if (grow < M) {
                    if (OUT_BF16)
                        ((unsigned short*)C)[(size_t)grow * ldc + gcol] = f2b(acc[mt][nt][r]);
                    else
                        ((float*)C)[(size_t)grow * ldc + gcol] = acc[mt][nt][r];
                }
            }
        }
    }
}

// ---------------- CSR build (merged branches, vectorized scan) ----------------
__global__ void build_csr(const void* __restrict__ A0, const void* __restrict__ A1) {
    int n = blockIdx.x;
    int which = n >= NN ? 1 : 0;
    const void* A = which ? A1 : A0;
    const int bf = g_dt[4 + which];
    int row = n - which * NN;
    __shared__ int c;
    if (threadIdx.x == 0) c = 0;
    __syncthreads();
    if (bf) {
        const uint2* p = (const uint2*)((const unsigned short*)A + (size_t)row * NN);
        for (int i = threadIdx.x; i < NN / 4; i += blockDim.x) {
            uint2 wv = p[i];
            unsigned v[4] = {wv.x & 0xFFFFu, wv.x >> 16, wv.y & 0xFFFFu, wv.y >> 16};
            #pragma unroll
            for (int r = 0; r < 4; r++) {
                unsigned b = v[r];
                if (b && !(b & 0x8000u)) {
                    int qq = atomicAdd(&c, 1);
                    if (qq < CAP) {
                        g_csri[(size_t)n * CAP + qq] = (unsigned)(i * 4 + r);
                        g_csrv[(size_t)n * CAP + qq] = __uint_as_float(b << 16);
                    }
                }
            }
        }
    } else {
        const float2* p = (const float2*)((const float*)A + (size_t)row * NN);
        for (int i = threadIdx.x; i < NN / 2; i += blockDim.x) {
            float2 wv = p[i];
            if (wv.x > 0.f) { int qq = atomicAdd(&c, 1); if (qq < CAP) {
                g_csri[(size_t)n * CAP + qq] = (unsigned)(i * 2); g_csrv[(size_t)n * CAP + qq] = wv.x; } }
            if (wv.y > 0.f) { int qq = atomicAdd(&c, 1); if (qq < CAP) {
                g_csri[(size_t)n * CAP + qq] = (unsigned)(i * 2 + 1); g_csrv[(size_t)n * CAP + qq] = wv.y; } }
        }
    }
    __syncthreads();
    if (threadIdx.x == 0) g_cnt[n] = min(c, CAP);
}

// ---------------- Relation aggregator (merged) ----------------
__global__ void rel_agg_kernel(const void* __restrict__ ra0, const void* __restrict__ ra1,
                               const void* __restrict__ re0, const void* __restrict__ re1,
                               float* __restrict__ out) {
    int n = blockIdx.x, d = threadIdx.x;
    int which = n >= NN ? 1 : 0;
    const void* radj = which ? ra1 : ra0;
    const void* rel  = which ? re1 : re0;
    const int bfa = g_dt[6 + which], bfr = g_dt[2 + which];
    int row = n - which * NN;
    __shared__ int list[CAPR];
    __shared__ int cs;
    if (d == 0) cs = 0;
    __syncthreads();
    for (int m = d; m < RR; m += 128) {
        float a = ldin(radj, (size_t)row * RR + m, bfa);
        if (a > 0.f) { int p = atomicAdd(&cs, 1); if (p < CAPR) list[p] = m; }
    }
    __syncthreads();
    int c = min(cs, CAPR);
    float acc = 0.f;
    for (int j = 0; j < c; j++) acc += ldin(rel, (size_t)list[j] * DD + d, bfr);
    float r = c ? acc / (float)c : 0.f;
    out[(size_t)n * 256 + 128 + d] = r;
    out[(size_t)(2 * NN + n) * 256 + 128 + d] = r;
}

// ---------------- GAT ----------------
__global__ void copy_ent_seq(const void* __restrict__ e0, const void* __restrict__ e1) {
    int n = blockIdx.x, d = threadIdx.x;
    int which = n >= NN ? 1 : 0;
    float v = ldin(which ? e1 : e0, (size_t)(n - which * NN) * DD + d, g_dt[which]);
    g_seq[(size_t)n * 384 + d] = v;
    g_seqb[(size_t)n * 384 + d] = f2b(v);
}

__global__ __launch_bounds__(256) void gat_scores(int layer, const void* __restrict__ a_src,
                                                  const void* __restrict__ a_dst) {
    int n = blockIdx.x, tid = threadIdx.x;
    int h = tid >> 7, e = tid & 127;
    const int bfs = g_dt[9], bfd = g_dt[10];
    __shared__ float red[256];
    float hv = b2f(g_hhb[(size_t)n * 256 + tid]);
    size_t abase = ((size_t)layer * 2 + h) * DD;
    red[tid] = hv * ldin(a_src, abase + e, bfs); __syncthreads();
    for (int s = 64; s > 0; s >>= 1) { if ((tid & 127) < s) red[tid] += red[tid + s]; __syncthreads(); }
    if ((tid & 127) == 0) g_es[h][n] = red[tid];
    __syncthreads();
    red[tid] = hv * ldin(a_dst, abase + e, bfd); __syncthreads();
    for (int s = 64; s > 0; s >>= 1) { if ((tid & 127) < s) red[tid] += red[tid + s]; __syncthreads(); }
    if ((tid & 127) == 0) g_ed[h][n] = red[tid];
}

__global__ void gat_attn(int layer) {
    int n = blockIdx.x, d = threadIdx.x;   // 128 threads
    int which = n >= NN ? 1 : 0;
    int c = g_cnt[n];
    __shared__ float w0s[CAP], w1s[CAP];
    __shared__ int   idxs[CAP];
    __shared__ float red[128];
    float es0 = g_es[0][n], es1 = g_es[1][n];
    float e0 = -1e30f, e1 = -1e30f;
    if (d < c) {
        int gI = (int)g_csri[(size_t)n * CAP + d] + which * NN;
        idxs[d] = gI;
        e0 = es0 + g_ed[0][gI]; e0 = e0 > 0.f ? e0 : 0.2f * e0;
        e1 = es1 + g_ed[1][gI]; e1 = e1 > 0.f ? e1 : 0.2f * e1;
    }
    float m0 = block_reduce_max128(e0, red);
    float m1 = block_reduce_max128(e1, red);
    float w0 = (d < c) ? expf(e0 - m0) : 0.f;
    float w1 = (d < c) ? expf(e1 - m1) : 0.f;
    float s0 = block_reduce_sum128(w0, red);
    float s1 = block_reduce_sum128(w1, red);
    if (d < c) { w0s[d] = w0 / fmaxf(s0, 1e-30f); w1s[d] = w1 / fmaxf(s1, 1e-30f); }
    __syncthreads();
    float a0 = 0.f, a1 = 0.f;
    for (int j = 0; j < c; j++) {
        size_t base = (size_t)idxs[j] * 256;
        a0 = fmaf(w0s[j], b2f(g_hhb[base + d]), a0);
        a1 = fmaf(w1s[j], b2f(g_hhb[base + 128 + d]), a1);
    }
    float o = (c > 0) ? 0.5f * (a0 + a1) : 0.f;
    o = o > 0.f ? o : expm1f(o);            // elu
    float ss = block_reduce_sum128(o * o, red);
    float r = o / fmaxf(sqrtf(ss), 1e-12f);
    g_seq[(size_t)n * 384 + (layer + 1) * 128 + d] = r;
    g_seqb[(size_t)n * 384 + (layer + 1) * 128 + d] = f2b(r);
}

// ---------------- MHA ----------------
__global__ __launch_bounds__(256) void mha_attn() {
    int n = blockIdx.x, tid = threadIdx.x;
    __shared__ float qs[3][256], ks[3][256], vs[3][256], os[3][256];
    __shared__ float att[2][3][3];
    const unsigned* src = (const unsigned*)(g_qkvb + (size_t)n * 3 * 768);
    for (int t = tid; t < 1152; t += 256) {   // 1152 u32 = 2304 bf16
        unsigned wv = src[t];
        int el = t * 2;
        int l = el / 768, e = el % 768;
        float f0 = b2f((unsigned short)(wv & 0xFFFFu));
        float f1 = b2f((unsigned short)(wv >> 16));
        if (e < 256)      { qs[l][e] = f0;       qs[l][e + 1] = f1; }
        else if (e < 512) { ks[l][e - 256] = f0; ks[l][e - 255] = f1; }
        else              { vs[l][e - 512] = f0; vs[l][e - 511] = f1; }
    }
    __syncthreads();
    if (tid < 18) {
        int h = tid / 9, lm = tid % 9, l = lm / 3, m = lm % 3;
        float acc = 0.f;
        for (int d = 0; d < 128; d++) acc += qs[l][h * 128 + d] * ks[m][h * 128 + d];
        att[h][l][m] = acc * 0.08838834764831845f;
    }
    __syncthreads();
    if (tid < 6) {
        int h = tid / 3, l = tid % 3;
        float mx = fmaxf(att[h][l][0], fmaxf(att[h][l][1], att[h][l][2]));
        float e0 = expf(att[h][l][0] - mx), e1 = expf(att[h][l][1] - mx), e2 = expf(att[h][l][2] - mx);
        float s = fmaxf(e0 + e1 + e2, 1e-30f);
        att[h][l][0] = e0 / s; att[h][l][1] = e1 / s; att[h][l][2] = e2 / s;
    }
    __syncthreads();
    for (int t = tid; t < 768; t += 256) {
        int l = t >> 8, e = t & 255, h = e >> 7;
        os[l][e] = att[h][l][0] * vs[0][e] + att[h][l][1] * vs[1][e] + att[h][l][2] * vs[2][e];
    }
    __syncthreads();
    unsigned* dst = (unsigned*)(g_ob + (size_t)n * 3 * 256);
    for (int t = tid; t < 384; t += 256) {    // pack pairs
        int l = t / 128, e2 = (t % 128) * 2;
        dst[t] = (unsigned)f2b(os[l][e2]) | ((unsigned)f2b(os[l][e2 + 1]) << 16);
    }
}

__global__ void mha_out(const void* __restrict__ g, const void* __restrict__ b,
                        float* __restrict__ out) {
    int n = blockIdx.x, d = threadIdx.x;
    const int bg = g_dt[15], bb = g_dt[16];
    __shared__ float red[128];
    float ool[3], mu[3], rstd[3];
    #pragma unroll
    for (int l = 0; l < 3; l++)
        ool[l] = g_fc[(size_t)(n * 3 + l) * 128 + d] + g_seq[(size_t)(n * 3 + l) * 128 + d];
    #pragma unroll
    for (int l = 0; l < 3; l++) {
        float s  = block_reduce_sum128(ool[l], red);
        float ss = block_reduce_sum128(ool[l] * ool[l], red);
        mu[l] = s / 128.f;
        rstd[l] = rsqrtf(ss / 128.f - mu[l] * mu[l] + 1e-6f);
    }
    float acc = 0.f;
    #pragma unroll
    for (int l = 0; l < 3; l++) acc += (ool[l] - mu[l]) * rstd[l];
    out[(size_t)n * 256 + d] = ldin(g, d, bg) * (acc / 3.f) + ldin(b, d, bb);
}

// ---------------- Hyperbolic GCN (fused tangent-space formulation) ----------------
__global__ void hgc_bias(const void* __restrict__ hgc_b) {
    int i = blockIdx.x, d = threadIdx.x;
    __shared__ float red[128];
    float bv = ldin(hgc_b, (size_t)i * DD + d, g_dt[18]);
    float ss = block_reduce_sum128(bv * bv, red);
    float nrm = fmaxf(sqrtf(ss), 1e-15f);
    float t = tanhf(nrm);
    float v = t / nrm * bv;
    float vn = t;
    if (t > MAXN_F) { v *= MAXN_F / t; vn = MAXN_F; }
    g_hb[i][d] = v;
    if (d == 0) g_hb2[i] = vn * vn;
}

__global__ void hgc_linear(const void* __restrict__ e0, const void* __restrict__ e1, int layer) {
    int n = blockIdx.x, d = threadIdx.x;
    __shared__ float red[128];
    __shared__ float u[128];
    float uv;
    if (layer == 0) {
        int which = n >= NN ? 1 : 0;
        float x = ldin(which ? e1 : e0, (size_t)(n - which * NN) * DD + d, g_dt[which]);
        float ss = block_reduce_sum128(x * x, red);
        float nrm = fmaxf(sqrtf(ss), 1e-15f);
        float t = tanhf(nrm);
        float scale = t / nrm;
        float hn = t;
        if (t > MAXN_F) { scale *= MAXN_F / t; hn = MAXN_F; }
        uv = atanhf(fminf(hn, 1.f - 1e-7f)) / fmaxf(hn, 1e-15f) * (scale * x);
    } else {
        uv = g_u[(size_t)n * DD + d];
    }
    u[d] = uv; __syncthreads();
    const float* W = &g_Whgc[layer][d * DD];
    float mv = 0.f;
    #pragma unroll
    for (int j = 0; j < DD; j += 4) {
        float4 wv = *(const float4*)(W + j);
        float4 uu = *(const float4*)(&u[j]);
        mv = fmaf(wv.x, uu.x, fmaf(wv.y, uu.y, fmaf(wv.z, uu.z, fmaf(wv.w, uu.w, mv))));
    }
    float ss2 = block_reduce_sum128(mv * mv, red);
    float nm = fmaxf(sqrtf(ss2), 1e-15f);
    float t2 = tanhf(nm);
    float x = t2 / nm * mv;
    float xn = t2;
    if (t2 > MAXN_F) { x *= MAXN_F / t2; xn = MAXN_F; }
    float y = g_hb[layer][d];
    float x2 = xn * xn;
    float y2 = g_hb2[layer];
    float xy = block_reduce_sum128(x * y, red);
    float num = (1.f + 2.f * xy + y2) * x + (1.f - x2) * y;
    float den = 1.f + 2.f * xy + x2 * y2;
    den = (fabsf(den) < 1e-15f) ? 1e-15f : den;
    float hv2 = num / den;
    float s3 = block_reduce_sum128(hv2 * hv2, red);
    float nn = fmaxf(sqrtf(s3), 1e-15f);
    if (nn > MAXN_F) { hv2 *= MAXN_F / nn; nn = MAXN_F; }
    float sc3 = atanhf(fminf(nn, 1.f - 1e-7f)) / nn;
    g_t[(size_t)n * DD + d] = sc3 * hv2;
}

__global__ void hgc_agg(int layer, const void* __restrict__ e0, const void* __restrict__ e1,
                        float* __restrict__ out) {
    int n = blockIdx.x, d = threadIdx.x;
    int which = n >= NN ? 1 : 0;
    __shared__ float red[128];
    int c = g_cnt[n];
    float acc = 0.f;
    for (int j = 0; j < c; j++) {
        acc = fmaf(g_csrv[(size_t)n * CAP + j],
                   g_t[((size_t)g_csri[(size_t)n * CAP + j] + which * NN) * DD + d], acc);
    }
    float ss = block_reduce_sum128(acc * acc, red);
    float nm = fmaxf(sqrtf(ss), 1e-15f);
    float t = tanhf(nm);
    float x = t / nm * acc;
    float xn = t;
    if (t > MAXN_F) { x *= MAXN_F / t; xn = MAXN_F; }
    float u = atanhf(fminf(xn, 1.f - 1e-7f)) / fmaxf(xn, 1e-15f) * x;
    u = fmaxf(u, 0.f);
    float ss2 = block_reduce_sum128(u * u, red);
    float nm2 = fmaxf(sqrtf(ss2), 1e-15f);
    float t2 = tanhf(nm2);
    float x2 = t2 / nm2 * u;
    float xn2 = t2;
    if (t2 > MAXN_F) { x2 *= MAXN_F / t2; xn2 = MAXN_F; }
    float u3 = atanhf(fminf(xn2, 1.f - 1e-7f)) / fmaxf(xn2, 1e-15f) * x2;
    if (layer == 0) {
        g_u[(size_t)n * DD + d] = u3;
    } else {
        float ev = ldin(which ? e1 : e0, (size_t)(n - which * NN) * DD + d, g_dt[which]);
        out[(size_t)(2 * NN + n) * 256 + d] = ev + u3;
    }
}

extern "C" void kernel_launch(void* const* d_in, const int* in_sizes, int n_in,
                              void* d_out, int out_size, void* d_ws, size_t ws_size,
                              hipStream_t stream) {
    const void* ent_sr = d_in[0];
    const void* ent_tg = d_in[1];
    const void* rel_sr = d_in[2];
    const void* rel_tg = d_in[3];
    const void* adj_sr = d_in[4];
    const void* adj_tg = d_in[5];
    const void* rel_adj_sr = d_in[6];
    const void* rel_adj_tg = d_in[7];
    const void* gat_W     = d_in[8];
    const void* gat_a_src = d_in[9];
    const void* gat_a_dst = d_in[10];
    const void* Wq  = d_in[11];
    const void* Wk  = d_in[12];
    const void* Wv  = d_in[13];
    const void* Wfc = d_in[14];
    const void* ln_g = d_in[15];
    const void* ln_b = d_in[16];
    const void* hgc_W = d_in[17];
    const void* hgc_b = d_in[18];

    float* out = (float*)d_out;

    unsigned short *p_seqb, *p_hhb, *p_qkvb, *p_ob, *p_WgatT, *p_WqkvT, *p_WfcT;
    float *p_fc;
    hipGetSymbolAddress((void**)&p_seqb,  HIP_SYMBOL(g_seqb));
    hipGetSymbolAddress((void**)&p_hhb,   HIP_SYMBOL(g_hhb));
    hipGetSymbolAddress((void**)&p_qkvb,  HIP_SYMBOL(g_qkvb));
    hipGetSymbolAddress((void**)&p_ob,    HIP_SYMBOL(g_ob));
    hipGetSymbolAddress((void**)&p_WgatT, HIP_SYMBOL(g_WgatT));
    hipGetSymbolAddress((void**)&p_WqkvT, HIP_SYMBOL(g_WqkvT));
    hipGetSymbolAddress((void**)&p_WfcT,  HIP_SYMBOL(g_WfcT));
    hipGetSymbolAddress((void**)&p_fc,    HIP_SYMBOL(g_fc));

    P19 ptrs;
    for (int i = 0; i < 19; i++) ptrs.p[i] = d_in[i];
    detect_all<<<19, 256, 0, stream>>>(ptrs);
    prep_weights<<<128, 256, 0, stream>>>(gat_W, Wq, Wk, Wv, Wfc, hgc_W);

    build_csr<<<N2, 256, 0, stream>>>(adj_sr, adj_tg);
    rel_agg_kernel<<<N2, 128, 0, stream>>>(rel_adj_sr, rel_adj_tg, rel_sr, rel_tg, out);

    copy_ent_seq<<<N2, 128, 0, stream>>>(ent_sr, ent_tg);
    for (int layer = 0; layer < 2; layer++) {
        // hh = seq[:,layer,:] @ Wgat[layer] : [12000 x 128] @ [128 x 256] -> bf16
        gemm_mfma<true><<<dim3(2, 94), 256, 0, stream>>>(
            p_seqb + layer * 128, 384, p_WgatT + (size_t)layer * 256 * DD, DD,
            p_hhb, 256, N2, 128);
        gat_scores<<<N2, 256, 0, stream>>>(layer, gat_a_src, gat_a_dst);
        gat_attn<<<N2, 128, 0, stream>>>(layer);
    }
    // qkv = seq @ Wqkv : [36000 x 128] @ [128 x 768] -> bf16
    gemm_mfma<true><<<dim3(6, 282), 256, 0, stream>>>(
        p_seqb, 128, p_WqkvT, DD, p_qkvb, 768, N2 * 3, 128);
    mha_attn<<<N2, 256, 0, stream>>>();
    // fc = o @ Wfc : [36000 x 256] @ [256 x 128] -> f32
    gemm_mfma<false><<<dim3(1, 282), 256, 0, stream>>>(
        p_ob, 256, p_WfcT, 256, p_fc, 128, N2 * 3, 256);
    mha_out<<<N2, 128, 0, stream>>>(ln_g, ln_b, out);

    hgc_bias<<<2, 128, 0, stream>>>(hgc_b);
    for (int layer = 0; layer < 2; layer++) {
        hgc_linear<<<N2, 128, 0, stream>>>(ent_sr, ent_tg, layer);
        hgc_agg<<<N2, 128, 0, stream>>>(layer, ent_sr, ent_tg, out);
    }
}

// Round 8
// 746.081 us; speedup vs baseline: 3.4154x; 1.1927x over previous
//
#include <hip/hip_runtime.h>
#include <hip/hip_bf16.h>
#include <math.h>

#define NN   6000
#define N2   12000
#define DD   128
#define RR   1000
#define CAP  96
#define CAPR 48
#define MAXN_F 0.996f
#define CSR_RPB 10

typedef short  bf16x8 __attribute__((ext_vector_type(8)));
typedef float  f32x4  __attribute__((ext_vector_type(4)));

// ---------------- module-global scratch ----------------
__device__ int      g_dt[19];
__device__ unsigned g_csri[N2 * CAP];
__device__ float    g_csrv[N2 * CAP];
__device__ int      g_cnt[N2];
__device__ float    g_seq[N2 * 3 * DD];
__device__ unsigned short g_seqb[N2 * 3 * DD];
__device__ unsigned short g_hhb[N2 * 256];
__device__ float    g_es[2][N2];
__device__ float    g_ed[2][N2];
__device__ unsigned short g_qkvb[(size_t)N2 * 3 * 768];
__device__ unsigned short g_ob[(size_t)N2 * 3 * 256];
__device__ float    g_fc[N2 * 3 * DD];
__device__ float    g_t[N2 * DD];    // hgc tangent stage 1
__device__ float    g_t2[N2 * DD];   // hgc tangent stage 2
__device__ float    g_hb[2][DD];
__device__ float    g_hb2[2];
// packed weights
__device__ unsigned short g_WgatT[2][256 * DD];
__device__ unsigned short g_WqkvT[768 * DD];
__device__ unsigned short g_WfcT[DD * 256];
__device__ float    g_WhgcT[2][DD * DD];   // [l][j*128+d] = W[l][d][j] (coalesced over d)

__device__ __forceinline__ float ldin(const void* p, size_t i, int bf) {
    if (bf) return __uint_as_float(((unsigned)((const unsigned short*)p)[i]) << 16);
    return ((const float*)p)[i];
}
__device__ __forceinline__ unsigned short f2b(float f) {
    unsigned u = __float_as_uint(f);
    u += 0x7FFFu + ((u >> 16) & 1u);
    return (unsigned short)(u >> 16);
}
__device__ __forceinline__ float b2f(unsigned short b) {
    return __uint_as_float(((unsigned)b) << 16);
}

// ---- wave64 shuffle reductions + 128-thread block combines (2 waves) ----
__device__ __forceinline__ float wsum(float v) {
    #pragma unroll
    for (int o = 32; o > 0; o >>= 1) v += __shfl_xor(v, o, 64);
    return v;
}
__device__ __forceinline__ float wmax(float v) {
    #pragma unroll
    for (int o = 32; o > 0; o >>= 1) v = fmaxf(v, __shfl_xor(v, o, 64));
    return v;
}
__device__ __forceinline__ float b128sum(float v, float* r4) {
    v = wsum(v);
    if ((threadIdx.x & 63) == 0) r4[threadIdx.x >> 6] = v;
    __syncthreads();
    float r = r4[0] + r4[1];
    __syncthreads();
    return r;
}
__device__ __forceinline__ void b128sum2(float v0, float v1, float* r4, float& o0, float& o1) {
    v0 = wsum(v0); v1 = wsum(v1);
    int w = threadIdx.x >> 6;
    if ((threadIdx.x & 63) == 0) { r4[w * 2] = v0; r4[w * 2 + 1] = v1; }
    __syncthreads();
    o0 = r4[0] + r4[2]; o1 = r4[1] + r4[3];
    __syncthreads();
}
__device__ __forceinline__ void b128max2(float v0, float v1, float* r4, float& o0, float& o1) {
    v0 = wmax(v0); v1 = wmax(v1);
    int w = threadIdx.x >> 6;
    if ((threadIdx.x & 63) == 0) { r4[w * 2] = v0; r4[w * 2 + 1] = v1; }
    __syncthreads();
    o0 = fmaxf(r4[0], r4[2]); o1 = fmaxf(r4[1], r4[3]);
    __syncthreads();
}

struct P19 { const void* p[19]; };

__global__ void detect_all(P19 ptrs) {
    const int sizes[19] = {768000,768000,128000,128000,36000000,36000000,6000000,6000000,
                           65536,512,512,32768,32768,32768,32768,128,128,32768,256};
    int slot = blockIdx.x;
    const unsigned* p = (const unsigned*)ptrs.p[slot];
    __shared__ int votes[2];
    if (threadIdx.x == 0) { votes[0] = 0; votes[1] = 0; }
    __syncthreads();
    int nwords = sizes[slot] / 2;
    if (nwords > 0) {
        int nsamp = nwords < 4096 ? nwords : 4096;
        int stride = nwords / nsamp; if (stride < 1) stride = 1;
        for (int s = threadIdx.x; s < nsamp; s += blockDim.x) {
            unsigned lo = p[(size_t)s * stride] & 0xFFFFu;
            if (lo) {
                unsigned e = (lo >> 7) & 0xFFu;
                if (e >= 100u && e <= 140u) atomicAdd(&votes[1], 1);
                else                        atomicAdd(&votes[0], 1);
            }
        }
    }
    __syncthreads();
    if (threadIdx.x == 0) g_dt[slot] = (votes[1] > votes[0]) ? 1 : 0;
}

__global__ void prep_weights(const void* gatW, const void* Wq, const void* Wk, const void* Wv,
                             const void* Wfc, const void* hgcW) {
    int stride = gridDim.x * blockDim.x;
    int base = blockIdx.x * blockDim.x + threadIdx.x;
    const int b8 = g_dt[8], b11 = g_dt[11], b12 = g_dt[12], b13 = g_dt[13],
              b14 = g_dt[14], b17 = g_dt[17];
    for (int i = base; i < 65536; i += stride) {
        int e = i & 127, d = (i >> 7) & 127, h = (i >> 14) & 1, l = (i >> 15) & 1;
        g_WgatT[l][(h * 128 + e) * DD + d] = f2b(ldin(gatW, i, b8));
    }
    for (int i = base; i < 32768; i += stride) {
        int d = i >> 8, e = i & 255;
        g_WqkvT[(size_t)e * DD + d]         = f2b(ldin(Wq, i, b11));
        g_WqkvT[(size_t)(256 + e) * DD + d] = f2b(ldin(Wk, i, b12));
        g_WqkvT[(size_t)(512 + e) * DD + d] = f2b(ldin(Wv, i, b13));
    }
    for (int i = base; i < 32768; i += stride) {
        int e = i >> 7, dd = i & 127;
        g_WfcT[dd * 256 + e] = f2b(ldin(Wfc, i, b14));
    }
    for (int i = base; i < 32768; i += stride) {      // hgc_W [l][d][j] -> [l][j][d]
        int j = i & 127, d = (i >> 7) & 127, l = i >> 14;
        g_WhgcT[l][j * 128 + d] = ldin(hgcW, i, b17);
    }
}

// ---------------- MFMA bf16 GEMM (unchanged from r7, verified) ----------------
template<bool OUT_BF16>
__global__ __launch_bounds__(256) void gemm_mfma(const unsigned short* __restrict__ A, int lda,
                                                 const unsigned short* __restrict__ Bt, int ldb,
                                                 void* __restrict__ C, int ldc, int M, int K) {
    __shared__ __align__(16) unsigned short As[16 * 128 * 8];
    __shared__ __align__(16) unsigned short Bs[16 * 128 * 8];
    int bm = blockIdx.y * 128, bn = blockIdx.x * 128;
    int tid = threadIdx.x;
    int lane = tid & 63, w = tid >> 6;
    int q = lane >> 4, ln = lane & 15;
    f32x4 acc[8][2] = {};
    for (int k0 = 0; k0 < K; k0 += 128) {
        if (k0 > 0) __syncthreads();
        #pragma unroll
        for (int i = 0; i < 8; i++) {
            int combo = w * 8 + i;
            int c = combo >> 1, half = combo & 1;
            int r = half * 64 + lane;
            int gm = bm + r; if (gm >= M) gm = M - 1;
            *(uint4*)&As[(c * 128 + r) * 8] =
                *(const uint4*)(A + (size_t)gm * lda + k0 + c * 8);
            *(uint4*)&Bs[(c * 128 + r) * 8] =
                *(const uint4*)(Bt + (size_t)(bn + r) * ldb + k0 + c * 8);
        }
        __syncthreads();
        #pragma unroll
        for (int s = 0; s < 4; s++) {
            bf16x8 bf0 = *(const bf16x8*)&Bs[((s * 4 + q) * 128 + w * 32 + ln) * 8];
            bf16x8 bf1 = *(const bf16x8*)&Bs[((s * 4 + q) * 128 + w * 32 + 16 + ln) * 8];
            #pragma unroll
            for (int mt = 0; mt < 8; mt++) {
                bf16x8 af = *(const bf16x8*)&As[((s * 4 + q) * 128 + mt * 16 + ln) * 8];
                acc[mt][0] = __builtin_amdgcn_mfma_f32_16x16x32_bf16(af, bf0, acc[mt][0], 0, 0, 0);
                acc[mt][1] = __builtin_amdgcn_mfma_f32_16x16x32_bf16(af, bf1, acc[mt][1], 0, 0, 0);
            }
        }
    }
    #pragma unroll
    for (int mt = 0; mt < 8; mt++) {
        #pragma unroll
        for (int nt = 0; nt < 2; nt++) {
            int gcol = bn + w * 32 + nt * 16 + ln;
            #pragma unroll
            for (int r = 0; r < 4; r++) {
                int grow = bm + mt * 16 + q * 4 + r;
                if (grow < M) {
                    if (OUT_BF16)
                        ((unsigned short*)C)[(size_t)grow * ldc + gcol] = f2b(acc[mt][nt][r]);
                    else
                        ((float*)C)[(size_t)grow * ldc + gcol] = acc[mt][nt][r];
                }
            }
        }
    }
}

// ---------------- CSR build: 10 contiguous rows per block, uint4 loads ----------------
__global__ void build_csr(const void* __restrict__ A0, const void* __restrict__ A1) {
    __shared__ int c;
    for (int rr = 0; rr < CSR_RPB; rr++) {
        int n = blockIdx.x * CSR_RPB + rr;
        int which = n >= NN ? 1 : 0;
        const void* A = which ? A1 : A0;
        const int bf = g_dt[4 + which];
        int row = n - which * NN;
        if (threadIdx.x == 0) c = 0;
        __syncthreads();
        if (bf) {
            const uint4* p = (const uint4*)((const unsigned short*)A + (size_t)row * NN);
            for (int i = threadIdx.x; i < NN / 8; i += 256) {
                uint4 w4 = p[i];
                unsigned ws[4] = {w4.x, w4.y, w4.z, w4.w};
                #pragma unroll
                for (int h = 0; h < 4; h++) {
                    unsigned lo = ws[h] & 0xFFFFu, hi = ws[h] >> 16;
                    if (lo && !(lo & 0x8000u)) {
                        int q = atomicAdd(&c, 1);
                        if (q < CAP) { g_csri[(size_t)n * CAP + q] = i * 8 + h * 2;
                                       g_csrv[(size_t)n * CAP + q] = __uint_as_float(lo << 16); }
                    }
                    if (hi && !(hi & 0x8000u)) {
                        int q = atomicAdd(&c, 1);
                        if (q < CAP) { g_csri[(size_t)n * CAP + q] = i * 8 + h * 2 + 1;
                                       g_csrv[(size_t)n * CAP + q] = __uint_as_float(hi << 16); }
                    }
                }
            }
        } else {
            const float4* p = (const float4*)((const float*)A + (size_t)row * NN);
            for (int i = threadIdx.x; i < NN / 4; i += 256) {
                float4 w4 = p[i];
                float vs[4] = {w4.x, w4.y, w4.z, w4.w};
                #pragma unroll
                for (int h = 0; h < 4; h++)
                    if (vs[h] > 0.f) {
                        int q = atomicAdd(&c, 1);
                        if (q < CAP) { g_csri[(size_t)n * CAP + q] = i * 4 + h;
                                       g_csrv[(size_t)n * CAP + q] = vs[h]; }
                    }
            }
        }
        __syncthreads();
        if (threadIdx.x == 0) g_cnt[n] = min(c, CAP);
        __syncthreads();
    }
}

// ---------------- Relation aggregator: uint4 scan ----------------
__global__ void rel_agg_kernel(const void* __restrict__ ra0, const void* __restrict__ ra1,
                               const void* __restrict__ re0, const void* __restrict__ re1,
                               float* __restrict__ out) {
    int n = blockIdx.x, d = threadIdx.x;
    int which = n >= NN ? 1 : 0;
    const void* radj = which ? ra1 : ra0;
    const void* rel  = which ? re1 : re0;
    const int bfa = g_dt[6 + which], bfr = g_dt[2 + which];
    int row = n - which * NN;
    __shared__ int list[CAPR];
    __shared__ int cs;
    if (d == 0) cs = 0;
    __syncthreads();
    if (bfa) {
        const uint4* p = (const uint4*)((const unsigned short*)radj + (size_t)row * RR);
        for (int i = d; i < RR / 8; i += 128) {
            uint4 w4 = p[i];
            unsigned ws[4] = {w4.x, w4.y, w4.z, w4.w};
            #pragma unroll
            for (int h = 0; h < 4; h++) {
                unsigned lo = ws[h] & 0xFFFFu, hi = ws[h] >> 16;
                if (lo && !(lo & 0x8000u)) { int q = atomicAdd(&cs, 1); if (q < CAPR) list[q] = i * 8 + h * 2; }
                if (hi && !(hi & 0x8000u)) { int q = atomicAdd(&cs, 1); if (q < CAPR) list[q] = i * 8 + h * 2 + 1; }
            }
        }
    } else {
        const float4* p = (const float4*)((const float*)radj + (size_t)row * RR);
        for (int i = d; i < RR / 4; i += 128) {
            float4 w4 = p[i];
            float vs[4] = {w4.x, w4.y, w4.z, w4.w};
            #pragma unroll
            for (int h = 0; h < 4; h++)
                if (vs[h] > 0.f) { int q = atomicAdd(&cs, 1); if (q < CAPR) list[q] = i * 4 + h; }
        }
    }
    __syncthreads();
    int c = min(cs, CAPR);
    float acc = 0.f;
    for (int j = 0; j < c; j++) acc += ldin(rel, (size_t)list[j] * DD + d, bfr);
    float r = c ? acc / (float)c : 0.f;
    out[(size_t)n * 256 + 128 + d] = r;
    out[(size_t)(2 * NN + n) * 256 + 128 + d] = r;
}

// ---------------- GAT ----------------
__global__ void copy_ent_seq(const void* __restrict__ e0, const void* __restrict__ e1) {
    int n = blockIdx.x, d = threadIdx.x;
    int which = n >= NN ? 1 : 0;
    float v = ldin(which ? e1 : e0, (size_t)(n - which * NN) * DD + d, g_dt[which]);
    g_seq[(size_t)n * 384 + d] = v;
    g_seqb[(size_t)n * 384 + d] = f2b(v);
}

__global__ __launch_bounds__(256) void gat_scores(int layer, const void* __restrict__ a_src,
                                                  const void* __restrict__ a_dst) {
    int n = blockIdx.x, tid = threadIdx.x;
    int h = tid >> 7, e = tid & 127;
    const int bfs = g_dt[9], bfd = g_dt[10];
    __shared__ float r8[8];
    float hv = b2f(g_hhb[(size_t)n * 256 + tid]);
    size_t abase = ((size_t)layer * 2 + h) * DD;
    float vs = wsum(hv * ldin(a_src, abase + e, bfs));
    float vd = wsum(hv * ldin(a_dst, abase + e, bfd));
    int w = tid >> 6;
    if ((tid & 63) == 0) { r8[w * 2] = vs; r8[w * 2 + 1] = vd; }
    __syncthreads();
    if (tid == 0)   { g_es[0][n] = r8[0] + r8[2]; g_ed[0][n] = r8[1] + r8[3]; }
    if (tid == 128) { g_es[1][n] = r8[4] + r8[6]; g_ed[1][n] = r8[5] + r8[7]; }
}

__global__ void gat_attn(int layer) {
    int n = blockIdx.x, d = threadIdx.x;   // 128 threads
    int which = n >= NN ? 1 : 0;
    int c = g_cnt[n];
    __shared__ float w0s[CAP], w1s[CAP];
    __shared__ unsigned bases[CAP];
    __shared__ float r4[4];
    __shared__ float sh[256];
    float es0 = g_es[0][n], es1 = g_es[1][n];
    float e0 = -1e30f, e1 = -1e30f;
    if (d < c) {
        int gI = (int)g_csri[(size_t)n * CAP + d] + which * NN;
        bases[d] = (unsigned)gI * 128u;    // u32 index into g_hhb-as-u32 (256 bf16 = 128 u32)
        e0 = es0 + g_ed[0][gI]; e0 = e0 > 0.f ? e0 : 0.2f * e0;
        e1 = es1 + g_ed[1][gI]; e1 = e1 > 0.f ? e1 : 0.2f * e1;
    }
    float m0, m1, s0, s1;
    b128max2(e0, e1, r4, m0, m1);
    float w0 = (d < c) ? expf(e0 - m0) : 0.f;
    float w1 = (d < c) ? expf(e1 - m1) : 0.f;
    b128sum2(w0, w1, r4, s0, s1);
    if (d < c) { w0s[d] = w0 / fmaxf(s0, 1e-30f); w1s[d] = w1 / fmaxf(s1, 1e-30f); }
    __syncthreads();
    // thread d accumulates packed elements (2d, 2d+1): head = d>>6
    const unsigned* hh32 = (const unsigned*)g_hhb;
    int head = d >> 6;
    float accLo = 0.f, accHi = 0.f;
    for (int j = 0; j < c; j++) {
        unsigned wv = hh32[(size_t)bases[j] + d];
        float wgt = head ? w1s[j] : w0s[j];
        accLo = fmaf(wgt, b2f((unsigned short)(wv & 0xFFFFu)), accLo);
        accHi = fmaf(wgt, b2f((unsigned short)(wv >> 16)), accHi);
    }
    sh[2 * d] = accLo; sh[2 * d + 1] = accHi;
    __syncthreads();
    float o = (c > 0) ? 0.5f * (sh[d] + sh[128 + d]) : 0.f;
    o = o > 0.f ? o : expm1f(o);           // elu
    __syncthreads();                        // sh reuse as r4 region is separate; protect sh reads done
    float ss = b128sum(o * o, r4);
    float r = o / fmaxf(sqrtf(ss), 1e-12f);
    g_seq[(size_t)n * 384 + (layer + 1) * 128 + d] = r;
    g_seqb[(size_t)n * 384 + (layer + 1) * 128 + d] = f2b(r);
}

// ---------------- MHA ----------------
__global__ __launch_bounds__(256) void mha_attn() {
    int n = blockIdx.x, tid = threadIdx.x;
    __shared__ float qs[3][256], ks[3][256], vs[3][256], os[3][256];
    __shared__ float att[2][3][3];
    const unsigned* src = (const unsigned*)(g_qkvb + (size_t)n * 3 * 768);
    for (int t = tid; t < 1152; t += 256) {
        unsigned wv = src[t];
        int el = t * 2;
        int l = el / 768, e = el % 768;
        float f0 = b2f((unsigned short)(wv & 0xFFFFu));
        float f1 = b2f((unsigned short)(wv >> 16));
        if (e < 256)      { qs[l][e] = f0;       qs[l][e + 1] = f1; }
        else if (e < 512) { ks[l][e - 256] = f0; ks[l][e - 255] = f1; }
        else              { vs[l][e - 512] = f0; vs[l][e - 511] = f1; }
    }
    __syncthreads();
    if (tid < 18) {
        int h = tid / 9, lm = tid % 9, l = lm / 3, m = lm % 3;
        float acc = 0.f;
        for (int d = 0; d < 128; d++) acc += qs[l][h * 128 + d] * ks[m][h * 128 + d];
        att[h][l][m] = acc * 0.08838834764831845f;
    }
    __syncthreads();
    if (tid < 6) {
        int h = tid / 3, l = tid % 3;
        float mx = fmaxf(att[h][l][0], fmaxf(att[h][l][1], att[h][l][2]));
        float e0 = expf(att[h][l][0] - mx), e1 = expf(att[h][l][1] - mx), e2 = expf(att[h][l][2] - mx);
        float s = fmaxf(e0 + e1 + e2, 1e-30f);
        att[h][l][0] = e0 / s; att[h][l][1] = e1 / s; att[h][l][2] = e2 / s;
    }
    __syncthreads();
    for (int t = tid; t < 768; t += 256) {
        int l = t >> 8, e = t & 255, h = e >> 7;
        os[l][e] = att[h][l][0] * vs[0][e] + att[h][l][1] * vs[1][e] + att[h][l][2] * vs[2][e];
    }
    __syncthreads();
    unsigned* dst = (unsigned*)(g_ob + (size_t)n * 3 * 256);
    for (int t = tid; t < 384; t += 256) {
        int l = t / 128, e2 = (t % 128) * 2;
        dst[t] = (unsigned)f2b(os[l][e2]) | ((unsigned)f2b(os[l][e2 + 1]) << 16);
    }
}

__global__ void mha_out(const void* __restrict__ g, const void* __restrict__ b,
                        float* __restrict__ out) {
    int n = blockIdx.x, d = threadIdx.x;
    const int bg = g_dt[15], bb = g_dt[16];
    __shared__ float r4[4];
    float ool[3], mu[3], rstd[3];
    #pragma unroll
    for (int l = 0; l < 3; l++)
        ool[l] = g_fc[(size_t)(n * 3 + l) * 128 + d] + g_seq[(size_t)(n * 3 + l) * 128 + d];
    #pragma unroll
    for (int l = 0; l < 3; l++) {
        float s, ss;
        b128sum2(ool[l], ool[l] * ool[l], r4, s, ss);
        mu[l] = s / 128.f;
        rstd[l] = rsqrtf(ss / 128.f - mu[l] * mu[l] + 1e-6f);
    }
    float acc = 0.f;
    #pragma unroll
    for (int l = 0; l < 3; l++) acc += (ool[l] - mu[l]) * rstd[l];
    out[(size_t)n * 256 + d] = ldin(g, d, bg) * (acc / 3.f) + ldin(b, d, bb);
}

// ---------------- Hyperbolic GCN ----------------
__global__ void hgc_bias(const void* __restrict__ hgc_b) {
    int i = blockIdx.x, d = threadIdx.x;
    __shared__ float r4[4];
    float bv = ldin(hgc_b, (size_t)i * DD + d, g_dt[18]);
    float ss = b128sum(bv * bv, r4);
    float nrm = fmaxf(sqrtf(ss), 1e-15f);
    float t = tanhf(nrm);
    float v = t / nrm * bv;
    float vn = t;
    if (t > MAXN_F) { v *= MAXN_F / t; vn = MAXN_F; }
    g_hb[i][d] = v;
    if (d == 0) g_hb2[i] = vn * vn;
}

// shared device helper: tangent u (LDS-visible) -> matvec W[layer] -> mobius(b) -> logmap -> outv
__device__ __forceinline__ float hgc_lin_core(float* u, float* r4, int layer, int d) {
    float mv = 0.f;
    #pragma unroll 4
    for (int j = 0; j < DD; j++) mv = fmaf(g_WhgcT[layer][j * 128 + d], u[j], mv);
    float ss2 = b128sum(mv * mv, r4);
    float nm = fmaxf(sqrtf(ss2), 1e-15f);
    float t2 = tanhf(nm);
    float x = t2 / nm * mv;
    float xn = t2;
    if (t2 > MAXN_F) { x *= MAXN_F / t2; xn = MAXN_F; }
    float y = g_hb[layer][d];
    float x2 = xn * xn;
    float y2 = g_hb2[layer];
    float xy = b128sum(x * y, r4);
    float num = (1.f + 2.f * xy + y2) * x + (1.f - x2) * y;
    float den = 1.f + 2.f * xy + x2 * y2;
    den = (fabsf(den) < 1e-15f) ? 1e-15f : den;
    float hv2 = num / den;
    float s3 = b128sum(hv2 * hv2, r4);
    float nn = fmaxf(sqrtf(s3), 1e-15f);
    if (nn > MAXN_F) { hv2 *= MAXN_F / nn; nn = MAXN_F; }
    return atanhf(fminf(nn, 1.f - 1e-7f)) / nn * hv2;
}

// CSR gather of tangent vectors -> expmap/proj -> log -> relu -> expmap/proj -> log
__device__ __forceinline__ float hgc_agg_core(const float* tin, int n, int which, float* r4, int d) {
    int c = g_cnt[n];
    float acc = 0.f;
    for (int j = 0; j < c; j++) {
        acc = fmaf(g_csrv[(size_t)n * CAP + j],
                   tin[((size_t)g_csri[(size_t)n * CAP + j] + which * NN) * DD + d], acc);
    }
    float ss = b128sum(acc * acc, r4);
    float nm = fmaxf(sqrtf(ss), 1e-15f);
    float t = tanhf(nm);
    float x = t / nm * acc;
    float xn = t;
    if (t > MAXN_F) { x *= MAXN_F / t; xn = MAXN_F; }
    float u = atanhf(fminf(xn, 1.f - 1e-7f)) / fmaxf(xn, 1e-15f) * x;
    u = fmaxf(u, 0.f);
    float ss2 = b128sum(u * u, r4);
    float nm2 = fmaxf(sqrtf(ss2), 1e-15f);
    float t2 = tanhf(nm2);
    float x2 = t2 / nm2 * u;
    float xn2 = t2;
    if (t2 > MAXN_F) { x2 *= MAXN_F / t2; xn2 = MAXN_F; }
    return atanhf(fminf(xn2, 1.f - 1e-7f)) / fmaxf(xn2, 1e-15f) * x2;
}

__global__ void hgc_lin0(const void* __restrict__ e0, const void* __restrict__ e1) {
    int n = blockIdx.x, d = threadIdx.x;
    int which = n >= NN ? 1 : 0;
    __shared__ float r4[4];
    __shared__ float u[128];
    float x = ldin(which ? e1 : e0, (size_t)(n - which * NN) * DD + d, g_dt[which]);
    float ss = b128sum(x * x, r4);
    float nrm = fmaxf(sqrtf(ss), 1e-15f);
    float t = tanhf(nrm);
    float scale = t / nrm;
    float hn = t;
    if (t > MAXN_F) { scale *= MAXN_F / t; hn = MAXN_F; }
    u[d] = atanhf(fminf(hn, 1.f - 1e-7f)) / fmaxf(hn, 1e-15f) * (scale * x);
    __syncthreads();
    g_t[(size_t)n * DD + d] = hgc_lin_core(u, r4, 0, d);
}

__global__ void hgc_mid() {   // agg(layer0) + linear(layer1) fused
    int n = blockIdx.x, d = threadIdx.x;
    int which = n >= NN ? 1 : 0;
    __shared__ float r4[4];
    __shared__ float u[128];
    float u3 = hgc_agg_core(g_t, n, which, r4, d);
    u[d] = u3;
    __syncthreads();
    g_t2[(size_t)n * DD + d] = hgc_lin_core(u, r4, 1, d);
}

__global__ void hgc_fin(const void* __restrict__ e0, const void* __restrict__ e1,
                        float* __restrict__ out) {
    int n = blockIdx.x, d = threadIdx.x;
    int which = n >= NN ? 1 : 0;
    __shared__ float r4[4];
    float u3 = hgc_agg_core(g_t2, n, which, r4, d);
    float ev = ldin(which ? e1 : e0, (size_t)(n - which * NN) * DD + d, g_dt[which]);
    out[(size_t)(2 * NN + n) * 256 + d] = ev + u3;
}

extern "C" void kernel_launch(void* const* d_in, const int* in_sizes, int n_in,
                              void* d_out, int out_size, void* d_ws, size_t ws_size,
                              hipStream_t stream) {
    const void* ent_sr = d_in[0];
    const void* ent_tg = d_in[1];
    const void* rel_sr = d_in[2];
    const void* rel_tg = d_in[3];
    const void* adj_sr = d_in[4];
    const void* adj_tg = d_in[5];
    const void* rel_adj_sr = d_in[6];
    const void* rel_adj_tg = d_in[7];
    const void* gat_W     = d_in[8];
    const void* gat_a_src = d_in[9];
    const void* gat_a_dst = d_in[10];
    const void* Wq  = d_in[11];
    const void* Wk  = d_in[12];
    const void* Wv  = d_in[13];
    const void* Wfc = d_in[14];
    const void* ln_g = d_in[15];
    const void* ln_b = d_in[16];
    const void* hgc_W = d_in[17];
    const void* hgc_b = d_in[18];

    float* out = (float*)d_out;

    unsigned short *p_seqb, *p_hhb, *p_qkvb, *p_ob, *p_WgatT, *p_WqkvT, *p_WfcT;
    float *p_fc;
    hipGetSymbolAddress((void**)&p_seqb,  HIP_SYMBOL(g_seqb));
    hipGetSymbolAddress((void**)&p_hhb,   HIP_SYMBOL(g_hhb));
    hipGetSymbolAddress((void**)&p_qkvb,  HIP_SYMBOL(g_qkvb));
    hipGetSymbolAddress((void**)&p_ob,    HIP_SYMBOL(g_ob));
    hipGetSymbolAddress((void**)&p_WgatT, HIP_SYMBOL(g_WgatT));
    hipGetSymbolAddress((void**)&p_WqkvT, HIP_SYMBOL(g_WqkvT));
    hipGetSymbolAddress((void**)&p_WfcT,  HIP_SYMBOL(g_WfcT));
    hipGetSymbolAddress((void**)&p_fc,    HIP_SYMBOL(g_fc));

    P19 ptrs;
    for (int i = 0; i < 19; i++) ptrs.p[i] = d_in[i];
    detect_all<<<19, 256, 0, stream>>>(ptrs);
    prep_weights<<<128, 256, 0, stream>>>(gat_W, Wq, Wk, Wv, Wfc, hgc_W);

    build_csr<<<N2 / CSR_RPB, 256, 0, stream>>>(adj_sr, adj_tg);
    rel_agg_kernel<<<N2, 128, 0, stream>>>(rel_adj_sr, rel_adj_tg, rel_sr, rel_tg, out);

    copy_ent_seq<<<N2, 128, 0, stream>>>(ent_sr, ent_tg);
    for (int layer = 0; layer < 2; layer++) {
        gemm_mfma<true><<<dim3(2, 94), 256, 0, stream>>>(
            p_seqb + layer * 128, 384, p_WgatT + (size_t)layer * 256 * DD, DD,
            p_hhb, 256, N2, 128);
        gat_scores<<<N2, 256, 0, stream>>>(layer, gat_a_src, gat_a_dst);
        gat_attn<<<N2, 128, 0, stream>>>(layer);
    }
    gemm_mfma<true><<<dim3(6, 282), 256, 0, stream>>>(
        p_seqb, 128, p_WqkvT, DD, p_qkvb, 768, N2 * 3, 128);
    mha_attn<<<N2, 256, 0, stream>>>();
    gemm_mfma<false><<<dim3(1, 282), 256, 0, stream>>>(
        p_ob, 256, p_WfcT, 256, p_fc, 128, N2 * 3, 256);
    mha_out<<<N2, 128, 0, stream>>>(ln_g, ln_b, out);

    hgc_bias<<<2, 128, 0, stream>>>(hgc_b);
    hgc_lin0<<<N2, 128, 0, stream>>>(ent_sr, ent_tg);
    hgc_mid<<<N2, 128, 0, stream>>>();
    hgc_fin<<<N2, 128, 0, stream>>>(ent_sr, ent_tg, out);
}